// Round 1
// baseline (2298.652 us; speedup 1.0000x reference)
//
#include <hip/hip_runtime.h>

// HolographicBlock: B=2, S=2048, D=1024, R=64, H=8, HD=128, half=64
// All f32 I/O; q/k/v staged as bf16 (ushort) in workspace.

#define Bn 2
#define Sn 2048
#define Dn 1024
#define Rn 64
#define Hn 8
#define HDn 128
#define Mn (Bn*Sn)   // 4096 rows

__device__ __forceinline__ float bf2f(unsigned short u){
    union { unsigned int i; float f; } x; x.i = ((unsigned int)u) << 16; return x.f;
}
__device__ __forceinline__ unsigned short f2bf(float f){
    union { float f; unsigned int i; } x; x.f = f;
    unsigned int r = x.i + 0x7fffu + ((x.i >> 16) & 1u);
    return (unsigned short)(r >> 16);
}

// ---------------- RMSNorm: out[m][d] = in[m][d] * rsqrt(mean(in^2)+EPS) * scale[d]
__global__ __launch_bounds__(256) void rms_kernel(const float* __restrict__ in,
                                                  const float* __restrict__ sc,
                                                  float* __restrict__ out){
    int m = blockIdx.x;
    const float4* in4 = (const float4*)(in + (size_t)m * Dn);
    float4 v = in4[threadIdx.x];                       // 256 threads * 4 = 1024
    float ss = v.x*v.x + v.y*v.y + v.z*v.z + v.w*v.w;
    for (int o = 32; o > 0; o >>= 1) ss += __shfl_down(ss, o);
    __shared__ float red[4];
    if ((threadIdx.x & 63) == 0) red[threadIdx.x >> 6] = ss;
    __syncthreads();
    float tot = red[0] + red[1] + red[2] + red[3];
    float r = rsqrtf(tot * (1.0f / Dn) + 1.1920929e-07f);
    float4 s4 = ((const float4*)sc)[threadIdx.x];
    float4 o4 = make_float4(v.x*r*s4.x, v.y*r*s4.y, v.z*r*s4.z, v.w*r*s4.w);
    ((float4*)(out + (size_t)m * Dn))[threadIdx.x] = o4;
}

// ---------------- Down-proj: t[m][r] = sum_d in[m][d] * A[d][r]   (A row-major D x R)
__global__ __launch_bounds__(256) void down_kernel(const float* __restrict__ in,
                                                   const float* __restrict__ A,
                                                   float* __restrict__ t){
    int m = blockIdx.x;
    int lane = threadIdx.x & 63, w = threadIdx.x >> 6;
    const float* row = in + (size_t)m * Dn;
    float acc = 0.f;
    int d0 = w * 256;
    #pragma unroll 8
    for (int d = d0; d < d0 + 256; ++d) acc += row[d] * A[d * Rn + lane];
    __shared__ float part[4][64];
    part[w][lane] = acc;
    __syncthreads();
    if (threadIdx.x < 64)
        t[(size_t)m * Rn + threadIdx.x] = part[0][threadIdx.x] + part[1][threadIdx.x]
                                        + part[2][threadIdx.x] + part[3][threadIdx.x];
}

// ---------------- QKV up-proj: for row m, out_{q,k,v}[b,h,s,hd] as bf16
__global__ __launch_bounds__(256) void qkv_up_kernel(const float* __restrict__ t,
                                                     const float* __restrict__ Cq,
                                                     const float* __restrict__ Ck,
                                                     const float* __restrict__ Cv,
                                                     const float* __restrict__ Bm,
                                                     unsigned short* __restrict__ qo,
                                                     unsigned short* __restrict__ ko,
                                                     unsigned short* __restrict__ vo){
    int m = blockIdx.x;
    int b = m >> 11, s = m & (Sn - 1);
    __shared__ float tq[64], tk[64], tv[64];
    if (threadIdx.x < 64){
        float tval = t[(size_t)m * Rn + threadIdx.x];
        tq[threadIdx.x] = tval * Cq[threadIdx.x];
        tk[threadIdx.x] = tval * Ck[threadIdx.x];
        tv[threadIdx.x] = tval * Cv[threadIdx.x];
    }
    __syncthreads();
    float aq[4] = {0,0,0,0}, ak[4] = {0,0,0,0}, av[4] = {0,0,0,0};
    for (int r = 0; r < Rn; ++r){
        float q_ = tq[r], k_ = tk[r], v_ = tv[r];
        const float* brow = Bm + (size_t)r * Dn + threadIdx.x;
        #pragma unroll
        for (int kk = 0; kk < 4; ++kk){
            float bv = brow[kk * 256];
            aq[kk] += q_ * bv; ak[kk] += k_ * bv; av[kk] += v_ * bv;
        }
    }
    #pragma unroll
    for (int kk = 0; kk < 4; ++kk){
        int d = threadIdx.x + kk * 256;
        int h = d >> 7, hd = d & 127;
        size_t o = ((size_t)(b * Hn + h) * Sn + s) * HDn + hd;
        qo[o] = f2bf(aq[kk]); ko[o] = f2bf(ak[kk]); vo[o] = f2bf(av[kk]);
    }
}

// ---------------- RoPE in-place on q and k (bf16), rows = 2 * B*H*S, 4 rows/block
__global__ __launch_bounds__(256) void rope_kernel(unsigned short* __restrict__ q,
                                                   unsigned short* __restrict__ k){
    int row = blockIdx.x * 4 + (threadIdx.x >> 6);
    int lane = threadIdx.x & 63;
    unsigned short* buf = (row < Bn*Hn*Sn) ? q : k;
    int rr = row & (Bn*Hn*Sn - 1);
    int s = rr & (Sn - 1);
    unsigned short* p = buf + (size_t)rr * HDn;
    // inv_freq = 10000^{-lane/64}
    float inv = exp2f(-(float)lane * (13.287712379549449f / 64.0f));
    float fr = (float)s * inv;
    float sn, cs; sincosf(fr, &sn, &cs);
    float u1 = bf2f(p[lane]), u2 = bf2f(p[lane + 64]);
    p[lane]      = f2bf(u1 * cs + u2 * sn);
    p[lane + 64] = f2bf(-u1 * sn + u2 * cs);
}

// ---------------- Flash attention (f32 vector): block = 4 waves, 4 consecutive q rows
__global__ __launch_bounds__(256) void attn_kernel(const unsigned short* __restrict__ qb,
                                                   const unsigned short* __restrict__ kb,
                                                   const unsigned short* __restrict__ vb,
                                                   float* __restrict__ y){
    int bh = blockIdx.x;                    // 0..15
    int q0 = blockIdx.y * 4;
    int w = threadIdx.x >> 6, lane = threadIdx.x & 63;
    int b = bh >> 3, h = bh & 7;
    const unsigned short* qptr = qb + (size_t)bh * Sn * HDn;
    const unsigned short* kptr = kb + (size_t)bh * Sn * HDn;
    const unsigned short* vptr = vb + (size_t)bh * Sn * HDn;

    __shared__ float Kt[HDn][64];   // transposed K tile (conflict-free score reads)
    __shared__ float Vt[64][HDn];   // row-major V tile (conflict-free PV reads)
    __shared__ float qs[4][HDn];

    for (int i = threadIdx.x; i < 4 * HDn; i += 256){
        int r = i >> 7, d = i & 127;
        qs[r][d] = bf2f(qptr[(size_t)(q0 + r) * HDn + d]) * 0.08838834764831845f; // 1/sqrt(128)
    }
    int myq = q0 + w;
    int maxq = q0 + 3;
    float mrun = -INFINITY, lrun = 0.f, acc0 = 0.f, acc1 = 0.f;
    __syncthreads();

    for (int j0 = 0; j0 <= maxq; j0 += 64){
        {   // stage 64 keys: K transposed, V row-major
            int key = threadIdx.x >> 2, dc = (threadIdx.x & 3) * 32;
            const unsigned short* krow = kptr + (size_t)(j0 + key) * HDn + dc;
            const unsigned short* vrow = vptr + (size_t)(j0 + key) * HDn + dc;
            #pragma unroll
            for (int c = 0; c < 8; ++c){
                ushort4 kv = ((const ushort4*)krow)[c];
                Kt[dc + c*4 + 0][key] = bf2f(kv.x);
                Kt[dc + c*4 + 1][key] = bf2f(kv.y);
                Kt[dc + c*4 + 2][key] = bf2f(kv.z);
                Kt[dc + c*4 + 3][key] = bf2f(kv.w);
                ushort4 vv = ((const ushort4*)vrow)[c];
                float4 vf = make_float4(bf2f(vv.x), bf2f(vv.y), bf2f(vv.z), bf2f(vv.w));
                ((float4*)&Vt[key][dc])[c] = vf;
            }
        }
        __syncthreads();
        if (j0 <= myq){
            int key = j0 + lane;
            float s_ = 0.f;
            #pragma unroll 8
            for (int d = 0; d < HDn; ++d) s_ += qs[w][d] * Kt[d][lane];
            bool valid = key <= myq;
            s_ = valid ? s_ : -INFINITY;
            float tmax = s_;
            for (int o = 32; o > 0; o >>= 1) tmax = fmaxf(tmax, __shfl_xor(tmax, o));
            float mnew = fmaxf(mrun, tmax);
            float p = valid ? __expf(s_ - mnew) : 0.f;
            float psum = p;
            for (int o = 32; o > 0; o >>= 1) psum += __shfl_xor(psum, o);
            float corr = __expf(mrun - mnew);     // first iter: exp(-inf)=0
            lrun = lrun * corr + psum;
            acc0 *= corr; acc1 *= corr;
            for (int kk = 0; kk < 64; ++kk){
                float pk = __shfl(p, kk);
                acc0 += pk * Vt[kk][lane];
                acc1 += pk * Vt[kk][lane + 64];
            }
            mrun = mnew;
        }
        __syncthreads();
    }
    float invl = 1.f / lrun;
    size_t yo = ((size_t)(b * Sn + myq)) * Dn + h * HDn;
    y[yo + lane]      = acc0 * invl;
    y[yo + lane + 64] = acc1 * invl;
}

// ---------------- Up-proj: out[m][d] = (base? base[m][d] : 0) + f(sum_r t[m][r]*C[r]*B[r][d])
__global__ __launch_bounds__(256) void up_kernel(const float* __restrict__ t,
                                                 const float* __restrict__ C,
                                                 const float* __restrict__ Bm,
                                                 const float* base,
                                                 float* out,
                                                 int silu){
    int m = blockIdx.x;
    __shared__ float ts[64];
    if (threadIdx.x < 64) ts[threadIdx.x] = t[(size_t)m * Rn + threadIdx.x] * C[threadIdx.x];
    __syncthreads();
    float a0 = 0.f, a1 = 0.f, a2 = 0.f, a3 = 0.f;
    for (int r = 0; r < Rn; ++r){
        float tv = ts[r];
        const float* brow = Bm + (size_t)r * Dn + threadIdx.x;
        a0 += tv * brow[0];
        a1 += tv * brow[256];
        a2 += tv * brow[512];
        a3 += tv * brow[768];
    }
    float vals[4] = {a0, a1, a2, a3};
    size_t o = (size_t)m * Dn + threadIdx.x;
    #pragma unroll
    for (int kk = 0; kk < 4; ++kk){
        float v_ = vals[kk];
        if (silu) v_ = v_ / (1.f + __expf(-v_));
        if (base) v_ += base[o + kk * 256];
        out[o + kk * 256] = v_;
    }
}

extern "C" void kernel_launch(void* const* d_in, const int* in_sizes, int n_in,
                              void* d_out, int out_size, void* d_ws, size_t ws_size,
                              hipStream_t stream){
    const float* x      = (const float*)d_in[0];
    const float* A      = (const float*)d_in[1];
    const float* Bm     = (const float*)d_in[2];
    const float* C_q    = (const float*)d_in[3];
    const float* C_k    = (const float*)d_in[4];
    const float* C_v    = (const float*)d_in[5];
    const float* C_o    = (const float*)d_in[6];
    const float* C_fc   = (const float*)d_in[7];
    const float* C_proj = (const float*)d_in[8];
    const float* scale1 = (const float*)d_in[9];
    const float* scale2 = (const float*)d_in[10];
    float* out = (float*)d_out;

    // ws layout (floats): n1/y/n2 [4M] | t [256K] | qkv bf16 (3 * 4M ushort) / mbuf f32
    float* wsf = (float*)d_ws;
    float* n1   = wsf;                                  // 4 Mi floats
    float* tbuf = wsf + (size_t)Mn * Dn;                // 256 Ki floats
    unsigned short* qb = (unsigned short*)(tbuf + (size_t)Mn * Rn);
    unsigned short* kb = qb + (size_t)Mn * Dn;
    unsigned short* vb = kb + (size_t)Mn * Dn;
    float* mbuf = (float*)qb;                           // reused after attention

    // 1. n1 = rms(x, scale1)
    rms_kernel<<<Mn, 256, 0, stream>>>(x, scale1, n1);
    // 2. t = n1 @ A
    down_kernel<<<Mn, 256, 0, stream>>>(n1, A, tbuf);
    // 3. q,k,v (bf16, (b,h,s,hd))
    qkv_up_kernel<<<Mn, 256, 0, stream>>>(tbuf, C_q, C_k, C_v, Bm, qb, kb, vb);
    // 4. rope on q and k
    rope_kernel<<<(2 * Bn * Hn * Sn) / 4, 256, 0, stream>>>(qb, kb);
    // 5. attention -> y (reuse n1 buffer, layout (b,s,h*hd))
    attn_kernel<<<dim3(Bn * Hn, Sn / 4), 256, 0, stream>>>(qb, kb, vb, n1);
    // 6. t = y @ A
    down_kernel<<<Mn, 256, 0, stream>>>(n1, A, tbuf);
    // 7. x1 = x + blin_up(t, C_o)  -> d_out
    up_kernel<<<Mn, 256, 0, stream>>>(tbuf, C_o, Bm, x, out, 0);
    // 8. n2 = rms(x1, scale2) (reuse n1 slot)
    rms_kernel<<<Mn, 256, 0, stream>>>(out, scale2, n1);
    // 9. t = n2 @ A
    down_kernel<<<Mn, 256, 0, stream>>>(n1, A, tbuf);
    // 10. mbuf = silu(blin_up(t, C_fc))
    up_kernel<<<Mn, 256, 0, stream>>>(tbuf, C_fc, Bm, nullptr, mbuf, 1);
    // 11. t = mbuf @ A
    down_kernel<<<Mn, 256, 0, stream>>>(mbuf, A, tbuf);
    // 12. out = x1 + blin_up(t, C_proj)
    up_kernel<<<Mn, 256, 0, stream>>>(tbuf, C_proj, Bm, out, out, 0);
}

// Round 2
// 619.631 us; speedup vs baseline: 3.7097x; 3.7097x over previous
//
#include <hip/hip_runtime.h>

// HolographicBlock: B=2, S=2048, D=1024, R=64, H=8, HD=128, half=64
// f32 I/O; q/k/v staged as bf16; attention = MFMA flash attention.

#define Bn 2
#define Sn 2048
#define Dn 1024
#define Rn 64
#define Hn 8
#define HDn 128
#define Mn (Bn*Sn)   // 4096 rows

typedef __bf16 bf16x8 __attribute__((ext_vector_type(8)));
typedef float f32x4 __attribute__((ext_vector_type(4)));

__device__ __forceinline__ float bf2f(unsigned short u){
    union { unsigned int i; float f; } x; x.i = ((unsigned int)u) << 16; return x.f;
}
__device__ __forceinline__ unsigned short f2bf(float f){
    union { float f; unsigned int i; } x; x.f = f;
    unsigned int r = x.i + 0x7fffu + ((x.i >> 16) & 1u);
    return (unsigned short)(r >> 16);
}

// ---------------- RMSNorm
__global__ __launch_bounds__(256) void rms_kernel(const float* __restrict__ in,
                                                  const float* __restrict__ sc,
                                                  float* __restrict__ out){
    int m = blockIdx.x;
    const float4* in4 = (const float4*)(in + (size_t)m * Dn);
    float4 v = in4[threadIdx.x];
    float ss = v.x*v.x + v.y*v.y + v.z*v.z + v.w*v.w;
    for (int o = 32; o > 0; o >>= 1) ss += __shfl_down(ss, o);
    __shared__ float red[4];
    if ((threadIdx.x & 63) == 0) red[threadIdx.x >> 6] = ss;
    __syncthreads();
    float tot = red[0] + red[1] + red[2] + red[3];
    float r = rsqrtf(tot * (1.0f / Dn) + 1.1920929e-07f);
    float4 s4 = ((const float4*)sc)[threadIdx.x];
    float4 o4 = make_float4(v.x*r*s4.x, v.y*r*s4.y, v.z*r*s4.z, v.w*r*s4.w);
    ((float4*)(out + (size_t)m * Dn))[threadIdx.x] = o4;
}

// ---------------- Down-proj: t[m][r] = sum_d in[m][d] * A[d][r]
__global__ __launch_bounds__(256) void down_kernel(const float* __restrict__ in,
                                                   const float* __restrict__ A,
                                                   float* __restrict__ t){
    int m = blockIdx.x;
    int lane = threadIdx.x & 63, w = threadIdx.x >> 6;
    const float* row = in + (size_t)m * Dn;
    float acc = 0.f;
    int d0 = w * 256;
    #pragma unroll 8
    for (int d = d0; d < d0 + 256; ++d) acc += row[d] * A[d * Rn + lane];
    __shared__ float part[4][64];
    part[w][lane] = acc;
    __syncthreads();
    if (threadIdx.x < 64)
        t[(size_t)m * Rn + threadIdx.x] = part[0][threadIdx.x] + part[1][threadIdx.x]
                                        + part[2][threadIdx.x] + part[3][threadIdx.x];
}

// ---------------- QKV up-proj (bf16 out, layout [b,h,s,hd])
__global__ __launch_bounds__(256) void qkv_up_kernel(const float* __restrict__ t,
                                                     const float* __restrict__ Cq,
                                                     const float* __restrict__ Ck,
                                                     const float* __restrict__ Cv,
                                                     const float* __restrict__ Bm,
                                                     unsigned short* __restrict__ qo,
                                                     unsigned short* __restrict__ ko,
                                                     unsigned short* __restrict__ vo){
    int m = blockIdx.x;
    int b = m >> 11, s = m & (Sn - 1);
    __shared__ float tq[64], tk[64], tv[64];
    if (threadIdx.x < 64){
        float tval = t[(size_t)m * Rn + threadIdx.x];
        tq[threadIdx.x] = tval * Cq[threadIdx.x];
        tk[threadIdx.x] = tval * Ck[threadIdx.x];
        tv[threadIdx.x] = tval * Cv[threadIdx.x];
    }
    __syncthreads();
    float aq[4] = {0,0,0,0}, ak[4] = {0,0,0,0}, av[4] = {0,0,0,0};
    for (int r = 0; r < Rn; ++r){
        float q_ = tq[r], k_ = tk[r], v_ = tv[r];
        const float* brow = Bm + (size_t)r * Dn + threadIdx.x;
        #pragma unroll
        for (int kk = 0; kk < 4; ++kk){
            float bv = brow[kk * 256];
            aq[kk] += q_ * bv; ak[kk] += k_ * bv; av[kk] += v_ * bv;
        }
    }
    #pragma unroll
    for (int kk = 0; kk < 4; ++kk){
        int d = threadIdx.x + kk * 256;
        int h = d >> 7, hd = d & 127;
        size_t o = ((size_t)(b * Hn + h) * Sn + s) * HDn + hd;
        qo[o] = f2bf(aq[kk]); ko[o] = f2bf(ak[kk]); vo[o] = f2bf(av[kk]);
    }
}

// ---------------- RoPE in-place on q and k
__global__ __launch_bounds__(256) void rope_kernel(unsigned short* __restrict__ q,
                                                   unsigned short* __restrict__ k){
    int row = blockIdx.x * 4 + (threadIdx.x >> 6);
    int lane = threadIdx.x & 63;
    unsigned short* buf = (row < Bn*Hn*Sn) ? q : k;
    int rr = row & (Bn*Hn*Sn - 1);
    int s = rr & (Sn - 1);
    unsigned short* p = buf + (size_t)rr * HDn;
    float inv = exp2f(-(float)lane * (13.287712379549449f / 64.0f));
    float fr = (float)s * inv;
    float sn, cs; sincosf(fr, &sn, &cs);
    float u1 = bf2f(p[lane]), u2 = bf2f(p[lane + 64]);
    p[lane]      = f2bf(u1 * cs + u2 * sn);
    p[lane + 64] = f2bf(-u1 * sn + u2 * cs);
}

// ---------------- V transpose: [b,h,s,d] -> [b,h,d,s], 64x64 tiles, conflict-free
__global__ __launch_bounds__(256) void vtr_kernel(const unsigned short* __restrict__ v,
                                                  unsigned short* __restrict__ vt){
    int bh = blockIdx.x;
    int s0 = blockIdx.y * 64, d0 = blockIdx.z * 64;
    __shared__ unsigned short tile[64 * 72];
    // load: rows = s, cols = d; chunk-XOR swizzle with (srow>>3)
    #pragma unroll
    for (int pass = 0; pass < 2; ++pass){
        int c = threadIdx.x + pass * 256;
        int srow = c >> 3, c8 = c & 7;
        const unsigned short* src = v + ((size_t)bh * Sn + s0 + srow) * HDn + d0 + c8 * 8;
        ushort4 a = ((const ushort4*)src)[0], b = ((const ushort4*)src)[1];
        unsigned short* dst = tile + srow * 72 + ((c8 ^ (srow >> 3)) * 8);
        ((ushort4*)dst)[0] = a; ((ushort4*)dst)[1] = b;
    }
    __syncthreads();
    #pragma unroll
    for (int pass = 0; pass < 2; ++pass){
        int c = threadIdx.x + pass * 256;
        int drow = c >> 3, sc8 = c & 7;
        unsigned short valbuf[8];
        #pragma unroll
        for (int e = 0; e < 8; ++e){
            int srow = sc8 * 8 + e;
            valbuf[e] = tile[srow * 72 + (((drow >> 3) ^ (srow >> 3)) * 8) + (drow & 7)];
        }
        unsigned short* dst = vt + ((size_t)bh * HDn + d0 + drow) * Sn + s0 + sc8 * 8;
        ((ushort4*)dst)[0] = *(ushort4*)&valbuf[0];
        ((ushort4*)dst)[1] = *(ushort4*)&valbuf[4];
    }
}

// ---------------- MFMA flash attention
// block = 4 waves; wave w owns q rows [q0+16w, q0+16w+16); key tiles of 64.
// K LDS [64][128] bf16 swizzled; Vt LDS [128][64] bf16 swizzled; P per-wave [16][64] swizzled.
#define KBASE 0
#define VBASE 16384
#define PBASE 32768
__global__ __launch_bounds__(256) void attn_kernel(const unsigned short* __restrict__ qb,
                                                   const unsigned short* __restrict__ kb,
                                                   const unsigned short* __restrict__ vtb,
                                                   float* __restrict__ y){
    __shared__ uint4 smem4[40960 / 16];
    char* smem = (char*)smem4;
    int bh = blockIdx.x;
    int q0 = blockIdx.y * 64;
    int b = bh >> 3, h = bh & 7;
    int tid = threadIdx.x;
    int w = tid >> 6, lane = tid & 63;
    int l4 = lane >> 4, lm = lane & 15;

    // Q fragments (A operand): lane holds Q[q0+16w+lm][32df+8*l4 .. +8]
    const unsigned short* qg = qb + ((size_t)bh * Sn + q0 + w * 16 + lm) * HDn;
    bf16x8 qf[4];
    #pragma unroll
    for (int df = 0; df < 4; ++df)
        qf[df] = *(const bf16x8*)(qg + df * 32 + l4 * 8);

    f32x4 acc[8];
    #pragma unroll
    for (int dg = 0; dg < 8; ++dg) acc[dg] = (f32x4){0.f, 0.f, 0.f, 0.f};
    float mrun[4] = {-1e30f, -1e30f, -1e30f, -1e30f};
    float lrun[4] = {0.f, 0.f, 0.f, 0.f};

    const char* kgbase = (const char*)(kb + ((size_t)bh * Sn) * HDn);
    const char* vgbase = (const char*)(vtb + (size_t)bh * HDn * Sn);
    const float scale = 0.08838834764831845f;  // 1/sqrt(128)
    int wqmax = q0 + w * 16 + 15;

    for (int j0 = 0; j0 <= q0 + 63; j0 += 64){
        // ---- stage K tile [64 keys][128 d] (256 B rows, XOR swizzle)
        #pragma unroll
        for (int pass = 0; pass < 4; ++pass){
            int c = tid + pass * 256;
            int row = c >> 4, col = (c & 15) * 16;
            uint4 val = *(const uint4*)(kgbase + ((size_t)(j0 + row)) * 256 + col);
            *(uint4*)(smem + KBASE + row * 256 + (col ^ ((row & 7) << 4))) = val;
        }
        // ---- stage Vt tile [128 d][64 keys] (128 B rows, XOR swizzle)
        #pragma unroll
        for (int pass = 0; pass < 4; ++pass){
            int c = tid + pass * 256;
            int row = c >> 3, col = (c & 7) * 16;
            uint4 val = *(const uint4*)(vgbase + (size_t)row * (Sn * 2) + (size_t)j0 * 2 + col);
            *(uint4*)(smem + VBASE + row * 128 + (col ^ ((row & 7) << 4))) = val;
        }
        __syncthreads();

        if (j0 <= wqmax){
            // ---- scores: S[q][key] = Q . K^T, 4 key-column tiles of 16
            f32x4 sf[4];
            #pragma unroll
            for (int kc = 0; kc < 4; ++kc){
                sf[kc] = (f32x4){0.f, 0.f, 0.f, 0.f};
                #pragma unroll
                for (int df = 0; df < 4; ++df){
                    int krow = 16 * kc + lm;
                    bf16x8 kf = *(const bf16x8*)(smem + KBASE + krow * 256 +
                                  ((64 * df + 16 * l4) ^ ((krow & 7) << 4)));
                    sf[kc] = __builtin_amdgcn_mfma_f32_16x16x32_bf16(qf[df], kf, sf[kc], 0, 0, 0);
                }
            }
            // ---- mask + online softmax (rows = 4*l4+r, cols = 16*kc+lm)
            float sv[4][4];
            #pragma unroll
            for (int kc = 0; kc < 4; ++kc){
                #pragma unroll
                for (int r = 0; r < 4; ++r){
                    float s = sf[kc][r] * scale;
                    int j = j0 + 16 * kc + lm;
                    int qr = q0 + 16 * w + 4 * l4 + r;
                    sv[kc][r] = (j > qr) ? -1e30f : s;
                }
            }
            float cr[4];
            #pragma unroll
            for (int r = 0; r < 4; ++r){
                float mx = fmaxf(fmaxf(sv[0][r], sv[1][r]), fmaxf(sv[2][r], sv[3][r]));
                #pragma unroll
                for (int o = 8; o >= 1; o >>= 1) mx = fmaxf(mx, __shfl_xor(mx, o));
                float mnew = fmaxf(mrun[r], mx);
                cr[r] = __expf(mrun[r] - mnew);
                float ps = 0.f;
                #pragma unroll
                for (int kc = 0; kc < 4; ++kc){
                    float p = __expf(sv[kc][r] - mnew);
                    sv[kc][r] = p; ps += p;
                }
                #pragma unroll
                for (int o = 8; o >= 1; o >>= 1) ps += __shfl_xor(ps, o);
                lrun[r] = lrun[r] * cr[r] + ps;
                mrun[r] = mnew;
            }
            #pragma unroll
            for (int dg = 0; dg < 8; ++dg){
                acc[dg][0] *= cr[0]; acc[dg][1] *= cr[1];
                acc[dg][2] *= cr[2]; acc[dg][3] *= cr[3];
            }
            // ---- P (bf16) to per-wave LDS in A-layout position
            int pb = PBASE + w * 2048;
            #pragma unroll
            for (int kc = 0; kc < 4; ++kc){
                #pragma unroll
                for (int r = 0; r < 4; ++r){
                    int prow = 4 * l4 + r;
                    *(unsigned short*)(smem + pb + prow * 128 +
                        (((16 * kc + lm) * 2) ^ ((prow & 7) << 4))) = f2bf(sv[kc][r]);
                }
            }
            // ---- PV: y += P . V  (A = P frag, B = Vt frag)
            #pragma unroll
            for (int ks = 0; ks < 2; ++ks){
                bf16x8 pa = *(const bf16x8*)(smem + pb + lm * 128 +
                              ((64 * ks + 16 * l4) ^ ((lm & 7) << 4)));
                #pragma unroll
                for (int dg = 0; dg < 8; ++dg){
                    int vrow = 16 * dg + lm;
                    bf16x8 vf = *(const bf16x8*)(smem + VBASE + vrow * 128 +
                                  ((64 * ks + 16 * l4) ^ ((vrow & 7) << 4)));
                    acc[dg] = __builtin_amdgcn_mfma_f32_16x16x32_bf16(pa, vf, acc[dg], 0, 0, 0);
                }
            }
        }
        __syncthreads();
    }
    // ---- epilogue: y[b][qrow][h*128 + 16dg + lm]
    #pragma unroll
    for (int r = 0; r < 4; ++r){
        float inv = 1.f / lrun[r];
        int qr = q0 + 16 * w + 4 * l4 + r;
        float* yrow = y + ((size_t)b * Sn + qr) * Dn + h * HDn;
        #pragma unroll
        for (int dg = 0; dg < 8; ++dg)
            yrow[16 * dg + lm] = acc[dg][r] * inv;
    }
}

// ---------------- Up-proj
__global__ __launch_bounds__(256) void up_kernel(const float* __restrict__ t,
                                                 const float* __restrict__ C,
                                                 const float* __restrict__ Bm,
                                                 const float* base,
                                                 float* out,
                                                 int silu){
    int m = blockIdx.x;
    __shared__ float ts[64];
    if (threadIdx.x < 64) ts[threadIdx.x] = t[(size_t)m * Rn + threadIdx.x] * C[threadIdx.x];
    __syncthreads();
    float a0 = 0.f, a1 = 0.f, a2 = 0.f, a3 = 0.f;
    for (int r = 0; r < Rn; ++r){
        float tv = ts[r];
        const float* brow = Bm + (size_t)r * Dn + threadIdx.x;
        a0 += tv * brow[0];
        a1 += tv * brow[256];
        a2 += tv * brow[512];
        a3 += tv * brow[768];
    }
    float vals[4] = {a0, a1, a2, a3};
    size_t o = (size_t)m * Dn + threadIdx.x;
    #pragma unroll
    for (int kk = 0; kk < 4; ++kk){
        float v_ = vals[kk];
        if (silu) v_ = v_ / (1.f + __expf(-v_));
        if (base) v_ += base[o + kk * 256];
        out[o + kk * 256] = v_;
    }
}

extern "C" void kernel_launch(void* const* d_in, const int* in_sizes, int n_in,
                              void* d_out, int out_size, void* d_ws, size_t ws_size,
                              hipStream_t stream){
    const float* x      = (const float*)d_in[0];
    const float* A      = (const float*)d_in[1];
    const float* Bm     = (const float*)d_in[2];
    const float* C_q    = (const float*)d_in[3];
    const float* C_k    = (const float*)d_in[4];
    const float* C_v    = (const float*)d_in[5];
    const float* C_o    = (const float*)d_in[6];
    const float* C_fc   = (const float*)d_in[7];
    const float* C_proj = (const float*)d_in[8];
    const float* scale1 = (const float*)d_in[9];
    const float* scale2 = (const float*)d_in[10];
    float* out = (float*)d_out;

    // ws layout: n1/y/n2 f32 [4M] | t f32 [256K] | q,k,v,vt bf16 (4 x 4M ushort)
    float* wsf = (float*)d_ws;
    float* n1   = wsf;
    float* tbuf = wsf + (size_t)Mn * Dn;
    unsigned short* qb  = (unsigned short*)(tbuf + (size_t)Mn * Rn);
    unsigned short* kb  = qb + (size_t)Mn * Dn;
    unsigned short* vb  = kb + (size_t)Mn * Dn;
    unsigned short* vtb = vb + (size_t)Mn * Dn;
    float* mbuf = (float*)qb;   // reused after attention (q,k dead)

    rms_kernel<<<Mn, 256, 0, stream>>>(x, scale1, n1);
    down_kernel<<<Mn, 256, 0, stream>>>(n1, A, tbuf);
    qkv_up_kernel<<<Mn, 256, 0, stream>>>(tbuf, C_q, C_k, C_v, Bm, qb, kb, vb);
    rope_kernel<<<(2 * Bn * Hn * Sn) / 4, 256, 0, stream>>>(qb, kb);
    vtr_kernel<<<dim3(Bn * Hn, Sn / 64, HDn / 64), 256, 0, stream>>>(vb, vtb);
    attn_kernel<<<dim3(Bn * Hn, Sn / 64), 256, 0, stream>>>(qb, kb, vtb, n1);
    down_kernel<<<Mn, 256, 0, stream>>>(n1, A, tbuf);
    up_kernel<<<Mn, 256, 0, stream>>>(tbuf, C_o, Bm, x, out, 0);
    rms_kernel<<<Mn, 256, 0, stream>>>(out, scale2, n1);
    down_kernel<<<Mn, 256, 0, stream>>>(n1, A, tbuf);
    up_kernel<<<Mn, 256, 0, stream>>>(tbuf, C_fc, Bm, nullptr, mbuf, 1);
    down_kernel<<<Mn, 256, 0, stream>>>(mbuf, A, tbuf);
    up_kernel<<<Mn, 256, 0, stream>>>(tbuf, C_proj, Bm, out, out, 0);
}

// Round 3
// 288.786 us; speedup vs baseline: 7.9597x; 2.1456x over previous
//
#include <hip/hip_runtime.h>

// HolographicBlock: B=2, S=2048, D=1024, R=64, H=8, HD=128
// All projections = bf16 MFMA GEMMs; attention = MFMA flash attention.

#define Bn 2
#define Sn 2048
#define Dn 1024
#define Rn 64
#define Hn 8
#define HDn 128
#define Mn (Bn*Sn)   // 4096 rows

typedef __bf16 bf16x8 __attribute__((ext_vector_type(8)));
typedef float f32x4 __attribute__((ext_vector_type(4)));

__device__ __forceinline__ float bf2f(unsigned short u){
    union { unsigned int i; float f; } x; x.i = ((unsigned int)u) << 16; return x.f;
}
__device__ __forceinline__ unsigned short f2bf(float f){
    union { float f; unsigned int i; } x; x.f = f;
    unsigned int r = x.i + 0x7fffu + ((x.i >> 16) & 1u);
    return (unsigned short)(r >> 16);
}
__device__ __forceinline__ unsigned int pk2(float a, float b){
    return (unsigned int)f2bf(a) | ((unsigned int)f2bf(b) << 16);
}

// ---------------- prep: bf16 transposed weights + rope table
// At_v[r][d] = A[d][r] * scale_v[d]   (v=0: none, 1: scale1, 2: scale2)   [64][1024]
// Bt_u[d][r] = B[r][d] * C_u[r]                                           [1024][64]
// rt[s][f] = (cos, sin) of s * 10000^{-f/64}                              [2048][64]
__global__ __launch_bounds__(256) void prep_g(const float* __restrict__ A,
                                              const float* __restrict__ Bsrc,
                                              const float* __restrict__ Cq, const float* __restrict__ Ck,
                                              const float* __restrict__ Cv, const float* __restrict__ Co,
                                              const float* __restrict__ Cfc, const float* __restrict__ Cpr,
                                              const float* __restrict__ s1, const float* __restrict__ s2,
                                              unsigned short* __restrict__ At0, unsigned short* __restrict__ At1,
                                              unsigned short* __restrict__ At2,
                                              unsigned short* __restrict__ Btq, unsigned short* __restrict__ Btk,
                                              unsigned short* __restrict__ Btv, unsigned short* __restrict__ Bto,
                                              unsigned short* __restrict__ Btfc, unsigned short* __restrict__ Btpr,
                                              float2* __restrict__ rt){
    int idx = blockIdx.x * 256 + threadIdx.x;
    if (idx < 3 * 65536){
        int v = idx >> 16, e = idx & 65535;
        int r = e >> 10, d = e & 1023;
        float sc = (v == 0) ? 1.f : (v == 1 ? s1[d] : s2[d]);
        unsigned short val = f2bf(A[d * 64 + r] * sc);
        (v == 0 ? At0 : v == 1 ? At1 : At2)[e] = val;
    } else if (idx < 9 * 65536){
        int v = (idx - 3 * 65536) >> 16, e = idx & 65535;
        int d = e >> 6, r = e & 63;
        const float* C = v==0?Cq : v==1?Ck : v==2?Cv : v==3?Co : v==4?Cfc : Cpr;
        unsigned short val = f2bf(Bsrc[r * 1024 + d] * C[r]);
        (v==0?Btq : v==1?Btk : v==2?Btv : v==3?Bto : v==4?Btfc : Btpr)[e] = val;
    } else if (idx < 9 * 65536 + Sn * 64){
        int e = idx - 9 * 65536;
        int s = e >> 6, f = e & 63;
        float inv = exp2f(-(float)f * (13.287712379549449f / 64.0f));
        float fr = (float)s * inv;
        float sn, cs; sincosf(fr, &sn, &cs);
        rt[e] = make_float2(cs, sn);
    }
}

// ---------------- down GEMM: t[m][r] = (opt rms-scale) * sum_d in[m][d] * At[r][d]
// M-tile 64, N=64, K=1024 in chunks of 64; reg-prefetch staging.
template<int IN_BF16, int DO_RMS>
__global__ __launch_bounds__(256) void down_g(const void* __restrict__ inp,
                                              const unsigned short* __restrict__ At,
                                              unsigned short* __restrict__ tout){
    __shared__ char xt[8192];
    __shared__ char at[8192];
    __shared__ float rr[64];
    int tid = threadIdx.x;
    int m0 = blockIdx.x * 64;
    int row = tid >> 2, q4 = tid & 3;
    int w = tid >> 6, lane = tid & 63, l4 = lane >> 4, lm = lane & 15;
    int swz = (row & 7) << 4;
    float ss = 0.f;
    f32x4 acc[4];
    #pragma unroll
    for (int nt = 0; nt < 4; ++nt) acc[nt] = (f32x4){0.f,0.f,0.f,0.f};

    float4 xr[4]; uint4 xrb[2]; uint4 ar[2];
    #define LOADC(c) { int k0 = (c) * 64; \
        if (!IN_BF16){ const float4* s = (const float4*)((const float*)inp + (size_t)(m0+row)*1024 + k0 + q4*16); \
            xr[0]=s[0]; xr[1]=s[1]; xr[2]=s[2]; xr[3]=s[3]; } \
        else { const uint4* s = (const uint4*)((const unsigned short*)inp + (size_t)(m0+row)*1024 + k0 + q4*16); \
            xrb[0]=s[0]; xrb[1]=s[1]; } \
        const uint4* a = (const uint4*)(At + (size_t)row*1024 + k0 + q4*16); \
        ar[0]=a[0]; ar[1]=a[1]; }

    LOADC(0);
    for (int c = 0; c < 16; ++c){
        int b0 = row * 128 + ((q4 * 32) ^ swz);
        int b1 = row * 128 + ((q4 * 32 + 16) ^ swz);
        if (!IN_BF16){
            if (DO_RMS){
                #pragma unroll
                for (int i = 0; i < 4; ++i)
                    ss += xr[i].x*xr[i].x + xr[i].y*xr[i].y + xr[i].z*xr[i].z + xr[i].w*xr[i].w;
            }
            uint4 p0 = {pk2(xr[0].x,xr[0].y), pk2(xr[0].z,xr[0].w), pk2(xr[1].x,xr[1].y), pk2(xr[1].z,xr[1].w)};
            uint4 p1 = {pk2(xr[2].x,xr[2].y), pk2(xr[2].z,xr[2].w), pk2(xr[3].x,xr[3].y), pk2(xr[3].z,xr[3].w)};
            *(uint4*)(xt + b0) = p0; *(uint4*)(xt + b1) = p1;
        } else {
            *(uint4*)(xt + b0) = xrb[0]; *(uint4*)(xt + b1) = xrb[1];
        }
        *(uint4*)(at + b0) = ar[0]; *(uint4*)(at + b1) = ar[1];
        __syncthreads();
        if (c < 15) LOADC(c + 1);
        #pragma unroll
        for (int ks = 0; ks < 2; ++ks){
            int arow = 16 * w + lm;
            bf16x8 af = *(const bf16x8*)(xt + arow * 128 + ((ks*64 + l4*16) ^ ((arow & 7) << 4)));
            #pragma unroll
            for (int nt = 0; nt < 4; ++nt){
                int brow = nt * 16 + lm;
                bf16x8 bf = *(const bf16x8*)(at + brow * 128 + ((ks*64 + l4*16) ^ ((brow & 7) << 4)));
                acc[nt] = __builtin_amdgcn_mfma_f32_16x16x32_bf16(af, bf, acc[nt], 0, 0, 0);
            }
        }
        __syncthreads();
    }
    #undef LOADC
    if (DO_RMS){
        ss += __shfl_xor(ss, 1); ss += __shfl_xor(ss, 2);
        if (q4 == 0) rr[row] = rsqrtf(ss * (1.f / 1024.f) + 1.1920929e-07f);
        __syncthreads();
    }
    #pragma unroll
    for (int nt = 0; nt < 4; ++nt)
        #pragma unroll
        for (int r = 0; r < 4; ++r){
            int ml = 16 * w + 4 * l4 + r;
            float v = acc[nt][r];
            if (DO_RMS) v *= rr[ml];
            tout[(size_t)(m0 + ml) * 64 + nt * 16 + lm] = f2bf(v);
        }
}

// ---------------- up GEMM: out[m][n] = epi( sum_r t[m][r] * Bt[n][r] )
// M-tile 64 x N-chunk 256, K=64.
template<int SILU, int HASBASE, int OUT_BF16>
__global__ __launch_bounds__(256) void up_g(const unsigned short* __restrict__ tin,
                                            const unsigned short* __restrict__ Bt,
                                            const float* __restrict__ base,
                                            void* __restrict__ outp){
    __shared__ char tt[8192];
    __shared__ char bb[32768];
    int tid = threadIdx.x;
    int m0 = blockIdx.x * 64, n0 = blockIdx.y * 256;
    int w = tid >> 6, lane = tid & 63, l4 = lane >> 4, lm = lane & 15;
    {
        int row = tid >> 2, q4 = tid & 3;
        const uint4* s = (const uint4*)(tin + (size_t)(m0 + row) * 64 + q4 * 16);
        uint4 v0 = s[0], v1 = s[1];
        *(uint4*)(tt + row * 128 + ((q4 * 32) ^ ((row & 7) << 4))) = v0;
        *(uint4*)(tt + row * 128 + ((q4 * 32 + 16) ^ ((row & 7) << 4))) = v1;
    }
    {
        const uint4* s = (const uint4*)(Bt + (size_t)(n0 + tid) * 64);
        #pragma unroll
        for (int j = 0; j < 8; ++j){
            uint4 v = s[j];
            *(uint4*)(bb + tid * 128 + ((j * 16) ^ ((tid & 7) << 4))) = v;
        }
    }
    __syncthreads();
    bf16x8 af[2];
    #pragma unroll
    for (int ks = 0; ks < 2; ++ks){
        int arow = 16 * w + lm;
        af[ks] = *(const bf16x8*)(tt + arow * 128 + ((ks*64 + l4*16) ^ ((arow & 7) << 4)));
    }
    f32x4 acc[16];
    #pragma unroll
    for (int nt = 0; nt < 16; ++nt) acc[nt] = (f32x4){0.f,0.f,0.f,0.f};
    #pragma unroll
    for (int nt = 0; nt < 16; ++nt){
        int brow = nt * 16 + lm;
        #pragma unroll
        for (int ks = 0; ks < 2; ++ks){
            bf16x8 bf = *(const bf16x8*)(bb + brow * 128 + ((ks*64 + l4*16) ^ ((brow & 7) << 4)));
            acc[nt] = __builtin_amdgcn_mfma_f32_16x16x32_bf16(af[ks], bf, acc[nt], 0, 0, 0);
        }
    }
    #pragma unroll
    for (int nt = 0; nt < 16; ++nt)
        #pragma unroll
        for (int r = 0; r < 4; ++r){
            int m = m0 + 16 * w + 4 * l4 + r;
            int n = n0 + nt * 16 + lm;
            float v = acc[nt][r];
            if (SILU) v = v / (1.f + __expf(-v));
            if (HASBASE) v += base[(size_t)m * 1024 + n];
            if (OUT_BF16) ((unsigned short*)outp)[(size_t)m * 1024 + n] = f2bf(v);
            else          ((float*)outp)[(size_t)m * 1024 + n] = v;
        }
}

// ---------------- fused QKV up-proj + RoPE + V-transpose
// grid (64 m-tiles, 4 n-chunks of 256). q,k -> [b,h,s,hd] bf16; v -> [b,h,d,s] bf16.
__global__ __launch_bounds__(256) void qkv_g(const unsigned short* __restrict__ tin,
                                             const unsigned short* __restrict__ Btq,
                                             const unsigned short* __restrict__ Btk,
                                             const unsigned short* __restrict__ Btv,
                                             const float2* __restrict__ rt,
                                             unsigned short* __restrict__ qout,
                                             unsigned short* __restrict__ kout,
                                             unsigned short* __restrict__ vtout){
    __shared__ char tt[8192];
    __shared__ char bb[32768];
    int tid = threadIdx.x;
    int m0 = blockIdx.x * 64, n0 = blockIdx.y * 256;
    int b = m0 >> 11, s0 = m0 & (Sn - 1);
    int h0 = n0 >> 7;
    int w = tid >> 6, lane = tid & 63, l4 = lane >> 4, lm = lane & 15;
    {
        int row = tid >> 2, q4 = tid & 3;
        const uint4* s = (const uint4*)(tin + (size_t)(m0 + row) * 64 + q4 * 16);
        uint4 v0 = s[0], v1 = s[1];
        *(uint4*)(tt + row * 128 + ((q4 * 32) ^ ((row & 7) << 4))) = v0;
        *(uint4*)(tt + row * 128 + ((q4 * 32 + 16) ^ ((row & 7) << 4))) = v1;
    }
    #define STAGE_B(SRC) { const uint4* s = (const uint4*)((SRC) + (size_t)(n0 + tid) * 64); \
        _Pragma("unroll") for (int j = 0; j < 8; ++j){ uint4 v = s[j]; \
            *(uint4*)(bb + tid * 128 + ((j * 16) ^ ((tid & 7) << 4))) = v; } }
    STAGE_B(Btq);
    __syncthreads();
    bf16x8 af[2];
    #pragma unroll
    for (int ks = 0; ks < 2; ++ks){
        int arow = 16 * w + lm;
        af[ks] = *(const bf16x8*)(tt + arow * 128 + ((ks*64 + l4*16) ^ ((arow & 7) << 4)));
    }
    f32x4 acc[16];
    // rope tables for this lane (f depends only on nt&3, s on r)
    float2 cs[4][4];
    #pragma unroll
    for (int ntb = 0; ntb < 4; ++ntb)
        #pragma unroll
        for (int r = 0; r < 4; ++r)
            cs[ntb][r] = rt[(size_t)(s0 + 16*w + 4*l4 + r) * 64 + ntb * 16 + lm];

    #define MMUL() { _Pragma("unroll") for (int nt = 0; nt < 16; ++nt) acc[nt] = (f32x4){0.f,0.f,0.f,0.f}; \
        _Pragma("unroll") for (int nt = 0; nt < 16; ++nt){ int brow = nt * 16 + lm; \
            _Pragma("unroll") for (int ks = 0; ks < 2; ++ks){ \
                bf16x8 bf = *(const bf16x8*)(bb + brow * 128 + ((ks*64 + l4*16) ^ ((brow & 7) << 4))); \
                acc[nt] = __builtin_amdgcn_mfma_f32_16x16x32_bf16(af[ks], bf, acc[nt], 0, 0, 0); } } }

    #define ROPE() { _Pragma("unroll") for (int g = 0; g < 2; ++g) \
        _Pragma("unroll") for (int ntb = 0; ntb < 4; ++ntb){ int lo = g*8 + ntb, hi = lo + 4; \
            _Pragma("unroll") for (int r = 0; r < 4; ++r){ float2 c = cs[ntb][r]; \
                float a = acc[lo][r], bq = acc[hi][r]; \
                acc[lo][r] = a * c.x + bq * c.y; acc[hi][r] = -a * c.y + bq * c.x; } } }

    // bounce [m][n] then coalesced store to [b,h,s,hd]
    #define BOUNCE_STORE(DST) { \
        _Pragma("unroll") for (int nt = 0; nt < 16; ++nt) \
            _Pragma("unroll") for (int r = 0; r < 4; ++r){ \
                int nl = nt * 16 + lm, ml2 = 16 * w + 4 * l4 + r; \
                *(unsigned short*)(bb + ml2 * 512 + ((nl * 2) ^ ((ml2 & 7) << 4))) = f2bf(acc[nt][r]); } \
        __syncthreads(); \
        { int ml = tid >> 2, seg = tid & 3; \
          int head = h0 + (seg >> 1), hd0 = (seg & 1) * 64; \
          size_t dstbase = (((size_t)(b * 8 + head) * Sn + (s0 + ml)) * 128 + hd0); \
          _Pragma("unroll") for (int j = 0; j < 8; ++j){ \
              uint4 v = *(const uint4*)(bb + ml * 512 + ((seg * 128 + j * 16) ^ ((ml & 7) << 4))); \
              *(uint4*)((DST) + dstbase + j * 8) = v; } } \
        __syncthreads(); }

    // ---- Q
    MMUL(); ROPE();
    __syncthreads();
    BOUNCE_STORE(qout);
    // ---- K
    STAGE_B(Btk);
    __syncthreads();
    MMUL(); ROPE();
    __syncthreads();
    BOUNCE_STORE(kout);
    // ---- V (transposed store)
    STAGE_B(Btv);
    __syncthreads();
    MMUL();
    __syncthreads();
    #pragma unroll
    for (int nt = 0; nt < 16; ++nt)
        #pragma unroll
        for (int r = 0; r < 4; ++r){
            int nl = nt * 16 + lm, ml2 = 16 * w + 4 * l4 + r;
            *(unsigned short*)(bb + nl * 128 + ((ml2 * 2) ^ ((nl & 7) << 4))) = f2bf(acc[nt][r]);
        }
    __syncthreads();
    {
        int head = h0 + (tid >> 7), d = tid & 127;
        size_t dstbase = (((size_t)(b * 8 + head) * 128 + d) * Sn + s0);
        #pragma unroll
        for (int j = 0; j < 8; ++j){
            uint4 v = *(const uint4*)(bb + tid * 128 + ((j * 16) ^ ((tid & 7) << 4)));
            *(uint4*)(vtout + dstbase + j * 8) = v;
        }
    }
    #undef STAGE_B
    #undef MMUL
    #undef ROPE
    #undef BOUNCE_STORE
}

// ---------------- MFMA flash attention (unchanged from R2)
#define KBASE 0
#define VBASE 16384
#define PBASE 32768
__global__ __launch_bounds__(256) void attn_kernel(const unsigned short* __restrict__ qb,
                                                   const unsigned short* __restrict__ kb,
                                                   const unsigned short* __restrict__ vtb,
                                                   float* __restrict__ y){
    __shared__ uint4 smem4[40960 / 16];
    char* smem = (char*)smem4;
    int bh = blockIdx.x;
    int q0 = blockIdx.y * 64;
    int b = bh >> 3, h = bh & 7;
    int tid = threadIdx.x;
    int w = tid >> 6, lane = tid & 63;
    int l4 = lane >> 4, lm = lane & 15;

    const unsigned short* qg = qb + ((size_t)bh * Sn + q0 + w * 16 + lm) * HDn;
    bf16x8 qf[4];
    #pragma unroll
    for (int df = 0; df < 4; ++df)
        qf[df] = *(const bf16x8*)(qg + df * 32 + l4 * 8);

    f32x4 acc[8];
    #pragma unroll
    for (int dg = 0; dg < 8; ++dg) acc[dg] = (f32x4){0.f, 0.f, 0.f, 0.f};
    float mrun[4] = {-1e30f, -1e30f, -1e30f, -1e30f};
    float lrun[4] = {0.f, 0.f, 0.f, 0.f};

    const char* kgbase = (const char*)(kb + ((size_t)bh * Sn) * HDn);
    const char* vgbase = (const char*)(vtb + (size_t)bh * HDn * Sn);
    const float scale = 0.08838834764831845f;
    int wqmax = q0 + w * 16 + 15;

    for (int j0 = 0; j0 <= q0 + 63; j0 += 64){
        #pragma unroll
        for (int pass = 0; pass < 4; ++pass){
            int c = tid + pass * 256;
            int row = c >> 4, col = (c & 15) * 16;
            uint4 val = *(const uint4*)(kgbase + ((size_t)(j0 + row)) * 256 + col);
            *(uint4*)(smem + KBASE + row * 256 + (col ^ ((row & 7) << 4))) = val;
        }
        #pragma unroll
        for (int pass = 0; pass < 4; ++pass){
            int c = tid + pass * 256;
            int row = c >> 3, col = (c & 7) * 16;
            uint4 val = *(const uint4*)(vgbase + (size_t)row * (Sn * 2) + (size_t)j0 * 2 + col);
            *(uint4*)(smem + VBASE + row * 128 + (col ^ ((row & 7) << 4))) = val;
        }
        __syncthreads();

        if (j0 <= wqmax){
            f32x4 sf[4];
            #pragma unroll
            for (int kc = 0; kc < 4; ++kc){
                sf[kc] = (f32x4){0.f, 0.f, 0.f, 0.f};
                #pragma unroll
                for (int df = 0; df < 4; ++df){
                    int krow = 16 * kc + lm;
                    bf16x8 kf = *(const bf16x8*)(smem + KBASE + krow * 256 +
                                  ((64 * df + 16 * l4) ^ ((krow & 7) << 4)));
                    sf[kc] = __builtin_amdgcn_mfma_f32_16x16x32_bf16(qf[df], kf, sf[kc], 0, 0, 0);
                }
            }
            float sv[4][4];
            #pragma unroll
            for (int kc = 0; kc < 4; ++kc){
                #pragma unroll
                for (int r = 0; r < 4; ++r){
                    float s = sf[kc][r] * scale;
                    int j = j0 + 16 * kc + lm;
                    int qr = q0 + 16 * w + 4 * l4 + r;
                    sv[kc][r] = (j > qr) ? -1e30f : s;
                }
            }
            float cr[4];
            #pragma unroll
            for (int r = 0; r < 4; ++r){
                float mx = fmaxf(fmaxf(sv[0][r], sv[1][r]), fmaxf(sv[2][r], sv[3][r]));
                #pragma unroll
                for (int o = 8; o >= 1; o >>= 1) mx = fmaxf(mx, __shfl_xor(mx, o));
                float mnew = fmaxf(mrun[r], mx);
                cr[r] = __expf(mrun[r] - mnew);
                float ps = 0.f;
                #pragma unroll
                for (int kc = 0; kc < 4; ++kc){
                    float p = __expf(sv[kc][r] - mnew);
                    sv[kc][r] = p; ps += p;
                }
                #pragma unroll
                for (int o = 8; o >= 1; o >>= 1) ps += __shfl_xor(ps, o);
                lrun[r] = lrun[r] * cr[r] + ps;
                mrun[r] = mnew;
            }
            #pragma unroll
            for (int dg = 0; dg < 8; ++dg){
                acc[dg][0] *= cr[0]; acc[dg][1] *= cr[1];
                acc[dg][2] *= cr[2]; acc[dg][3] *= cr[3];
            }
            int pb = PBASE + w * 2048;
            #pragma unroll
            for (int kc = 0; kc < 4; ++kc){
                #pragma unroll
                for (int r = 0; r < 4; ++r){
                    int prow = 4 * l4 + r;
                    *(unsigned short*)(smem + pb + prow * 128 +
                        (((16 * kc + lm) * 2) ^ ((prow & 7) << 4))) = f2bf(sv[kc][r]);
                }
            }
            #pragma unroll
            for (int ks = 0; ks < 2; ++ks){
                bf16x8 pa = *(const bf16x8*)(smem + pb + lm * 128 +
                              ((64 * ks + 16 * l4) ^ ((lm & 7) << 4)));
                #pragma unroll
                for (int dg = 0; dg < 8; ++dg){
                    int vrow = 16 * dg + lm;
                    bf16x8 vf = *(const bf16x8*)(smem + VBASE + vrow * 128 +
                                  ((64 * ks + 16 * l4) ^ ((vrow & 7) << 4)));
                    acc[dg] = __builtin_amdgcn_mfma_f32_16x16x32_bf16(pa, vf, acc[dg], 0, 0, 0);
                }
            }
        }
        __syncthreads();
    }
    #pragma unroll
    for (int r = 0; r < 4; ++r){
        float inv = 1.f / lrun[r];
        int qr = q0 + 16 * w + 4 * l4 + r;
        float* yrow = y + ((size_t)b * Sn + qr) * Dn + h * HDn;
        #pragma unroll
        for (int dg = 0; dg < 8; ++dg)
            yrow[16 * dg + lm] = acc[dg][r] * inv;
    }
}

extern "C" void kernel_launch(void* const* d_in, const int* in_sizes, int n_in,
                              void* d_out, int out_size, void* d_ws, size_t ws_size,
                              hipStream_t stream){
    const float* x      = (const float*)d_in[0];
    const float* A      = (const float*)d_in[1];
    const float* Bm     = (const float*)d_in[2];
    const float* C_q    = (const float*)d_in[3];
    const float* C_k    = (const float*)d_in[4];
    const float* C_v    = (const float*)d_in[5];
    const float* C_o    = (const float*)d_in[6];
    const float* C_fc   = (const float*)d_in[7];
    const float* C_proj = (const float*)d_in[8];
    const float* scale1 = (const float*)d_in[9];
    const float* scale2 = (const float*)d_in[10];
    float* out = (float*)d_out;

    char* ws = (char*)d_ws;
    size_t off = 0;
    auto alloc = [&](size_t bytes)->char*{ char* p = ws + off; off += (bytes + 255) & ~(size_t)255; return p; };
    unsigned short* qb   = (unsigned short*)alloc((size_t)Mn * Dn * 2);   // 8MB
    unsigned short* kb   = (unsigned short*)alloc((size_t)Mn * Dn * 2);   // 8MB
    unsigned short* vtb  = (unsigned short*)alloc((size_t)Mn * Dn * 2);   // 8MB
    float*          y    = (float*)alloc((size_t)Mn * Dn * 4);            // 16MB
    unsigned short* tbuf = (unsigned short*)alloc((size_t)Mn * Rn * 2);   // 512KB
    unsigned short* At0  = (unsigned short*)alloc(65536 * 2);
    unsigned short* At1  = (unsigned short*)alloc(65536 * 2);
    unsigned short* At2  = (unsigned short*)alloc(65536 * 2);
    unsigned short* Btq  = (unsigned short*)alloc(65536 * 2);
    unsigned short* Btk  = (unsigned short*)alloc(65536 * 2);
    unsigned short* Btv  = (unsigned short*)alloc(65536 * 2);
    unsigned short* Bto  = (unsigned short*)alloc(65536 * 2);
    unsigned short* Btfc = (unsigned short*)alloc(65536 * 2);
    unsigned short* Btpr = (unsigned short*)alloc(65536 * 2);
    float2*         rt   = (float2*)alloc((size_t)Sn * 64 * 8);           // 1MB
    unsigned short* mb   = qb;  // overlay: q dead after attention

    prep_g<<<2816, 256, 0, stream>>>(A, Bm, C_q, C_k, C_v, C_o, C_fc, C_proj,
                                     scale1, scale2, At0, At1, At2,
                                     Btq, Btk, Btv, Bto, Btfc, Btpr, rt);
    // t1 = rms(x, s1) @ A   (scale folded into At1, rms fused)
    down_g<0, 1><<<Mn / 64, 256, 0, stream>>>(x, At1, tbuf);
    // q,k (roped) + v^T
    qkv_g<<<dim3(Mn / 64, 4), 256, 0, stream>>>(tbuf, Btq, Btk, Btv, rt, qb, kb, vtb);
    // attention
    attn_kernel<<<dim3(Bn * Hn, Sn / 64), 256, 0, stream>>>(qb, kb, vtb, y);
    // t2 = y @ A
    down_g<0, 0><<<Mn / 64, 256, 0, stream>>>(y, At0, tbuf);
    // x1 = x + t2 @ Bto
    up_g<0, 1, 0><<<dim3(Mn / 64, 4), 256, 0, stream>>>(tbuf, Bto, x, out);
    // t3 = rms(x1, s2) @ A  (At2)
    down_g<0, 1><<<Mn / 64, 256, 0, stream>>>(out, At2, tbuf);
    // mb = silu(t3 @ Btfc)  (bf16)
    up_g<1, 0, 1><<<dim3(Mn / 64, 4), 256, 0, stream>>>(tbuf, Btfc, nullptr, mb);
    // t4 = mb @ A
    down_g<1, 0><<<Mn / 64, 256, 0, stream>>>(mb, At0, tbuf);
    // out = x1 + t4 @ Btpr
    up_g<0, 1, 0><<<dim3(Mn / 64, 4), 256, 0, stream>>>(tbuf, Btpr, out, out);
}

// Round 4
// 213.887 us; speedup vs baseline: 10.7471x; 1.3502x over previous
//
#include <hip/hip_runtime.h>

// HolographicBlock: B=2, S=2048, D=1024, R=64, H=8, HD=128
// All projections = bf16 MFMA GEMMs (K-split down-proj, f32 partials);
// attention = paired-tile 8-wave MFMA flash attention with reg-prefetch staging.

#define Bn 2
#define Sn 2048
#define Dn 1024
#define Rn 64
#define Hn 8
#define HDn 128
#define Mn (Bn*Sn)   // 4096 rows
#define TSTRIDE ((size_t)Mn * Rn)   // per-split tpart stride (262144 floats)

typedef __bf16 bf16x8 __attribute__((ext_vector_type(8)));
typedef float f32x4 __attribute__((ext_vector_type(4)));

__device__ __forceinline__ float bf2f(unsigned short u){
    union { unsigned int i; float f; } x; x.i = ((unsigned int)u) << 16; return x.f;
}
__device__ __forceinline__ unsigned short f2bf(float f){
    union { float f; unsigned int i; } x; x.f = f;
    unsigned int r = x.i + 0x7fffu + ((x.i >> 16) & 1u);
    return (unsigned short)(r >> 16);
}
__device__ __forceinline__ unsigned int pk2(float a, float b){
    return (unsigned int)f2bf(a) | ((unsigned int)f2bf(b) << 16);
}

// ---------------- prep: bf16 transposed weights + rope table
__global__ __launch_bounds__(256) void prep_g(const float* __restrict__ A,
                                              const float* __restrict__ Bsrc,
                                              const float* __restrict__ Cq, const float* __restrict__ Ck,
                                              const float* __restrict__ Cv, const float* __restrict__ Co,
                                              const float* __restrict__ Cfc, const float* __restrict__ Cpr,
                                              const float* __restrict__ s1, const float* __restrict__ s2,
                                              unsigned short* __restrict__ At0, unsigned short* __restrict__ At1,
                                              unsigned short* __restrict__ At2,
                                              unsigned short* __restrict__ Btq, unsigned short* __restrict__ Btk,
                                              unsigned short* __restrict__ Btv, unsigned short* __restrict__ Bto,
                                              unsigned short* __restrict__ Btfc, unsigned short* __restrict__ Btpr,
                                              float2* __restrict__ rt){
    int idx = blockIdx.x * 256 + threadIdx.x;
    if (idx < 3 * 65536){
        int v = idx >> 16, e = idx & 65535;
        int r = e >> 10, d = e & 1023;
        float sc = (v == 0) ? 1.f : (v == 1 ? s1[d] : s2[d]);
        unsigned short val = f2bf(A[d * 64 + r] * sc);
        (v == 0 ? At0 : v == 1 ? At1 : At2)[e] = val;
    } else if (idx < 9 * 65536){
        int v = (idx - 3 * 65536) >> 16, e = idx & 65535;
        int d = e >> 6, r = e & 63;
        const float* C = v==0?Cq : v==1?Ck : v==2?Cv : v==3?Co : v==4?Cfc : Cpr;
        unsigned short val = f2bf(Bsrc[r * 1024 + d] * C[r]);
        (v==0?Btq : v==1?Btk : v==2?Btv : v==3?Bto : v==4?Btfc : Btpr)[e] = val;
    } else if (idx < 9 * 65536 + Sn * 64){
        int e = idx - 9 * 65536;
        int s = e >> 6, f = e & 63;
        float inv = exp2f(-(float)f * (13.287712379549449f / 64.0f));
        float fr = (float)s * inv;
        float sn, cs; sincosf(fr, &sn, &cs);
        rt[e] = make_float2(cs, sn);
    }
}

// ---------------- down GEMM (K-split): tpart[sp][m][r] = sum_{d in split} in[m][d] * At[r][d]
template<int IN_BF16, int WRITE_SS>
__global__ __launch_bounds__(256) void down_g(const void* __restrict__ inp,
                                              const unsigned short* __restrict__ At,
                                              float* __restrict__ tpart,
                                              float* __restrict__ sspart){
    __shared__ char xt[8192];
    __shared__ char at[8192];
    int tid = threadIdx.x;
    int m0 = blockIdx.x * 64, sp = blockIdx.y;
    int row = tid >> 2, q4 = tid & 3;
    int w = tid >> 6, lane = tid & 63, l4 = lane >> 4, lm = lane & 15;
    int swz = (row & 7) << 4;
    float ss = 0.f;
    f32x4 acc[4];
    #pragma unroll
    for (int nt = 0; nt < 4; ++nt) acc[nt] = (f32x4){0.f,0.f,0.f,0.f};

    float4 xr[4]; uint4 xrb[2]; uint4 ar[2];
    #define LOADC(c) { int k0 = sp * 256 + (c) * 64; \
        if (!IN_BF16){ const float4* s = (const float4*)((const float*)inp + (size_t)(m0+row)*1024 + k0 + q4*16); \
            xr[0]=s[0]; xr[1]=s[1]; xr[2]=s[2]; xr[3]=s[3]; } \
        else { const uint4* s = (const uint4*)((const unsigned short*)inp + (size_t)(m0+row)*1024 + k0 + q4*16); \
            xrb[0]=s[0]; xrb[1]=s[1]; } \
        const uint4* a = (const uint4*)(At + (size_t)row*1024 + k0 + q4*16); \
        ar[0]=a[0]; ar[1]=a[1]; }

    LOADC(0);
    for (int c = 0; c < 4; ++c){
        int b0 = row * 128 + ((q4 * 32) ^ swz);
        int b1 = row * 128 + ((q4 * 32 + 16) ^ swz);
        if (!IN_BF16){
            if (WRITE_SS){
                #pragma unroll
                for (int i = 0; i < 4; ++i)
                    ss += xr[i].x*xr[i].x + xr[i].y*xr[i].y + xr[i].z*xr[i].z + xr[i].w*xr[i].w;
            }
            uint4 p0 = {pk2(xr[0].x,xr[0].y), pk2(xr[0].z,xr[0].w), pk2(xr[1].x,xr[1].y), pk2(xr[1].z,xr[1].w)};
            uint4 p1 = {pk2(xr[2].x,xr[2].y), pk2(xr[2].z,xr[2].w), pk2(xr[3].x,xr[3].y), pk2(xr[3].z,xr[3].w)};
            *(uint4*)(xt + b0) = p0; *(uint4*)(xt + b1) = p1;
        } else {
            *(uint4*)(xt + b0) = xrb[0]; *(uint4*)(xt + b1) = xrb[1];
        }
        *(uint4*)(at + b0) = ar[0]; *(uint4*)(at + b1) = ar[1];
        __syncthreads();
        if (c < 3) LOADC(c + 1);
        #pragma unroll
        for (int ks = 0; ks < 2; ++ks){
            int arow = 16 * w + lm;
            bf16x8 af = *(const bf16x8*)(xt + arow * 128 + ((ks*64 + l4*16) ^ ((arow & 7) << 4)));
            #pragma unroll
            for (int nt = 0; nt < 4; ++nt){
                int brow = nt * 16 + lm;
                bf16x8 bf = *(const bf16x8*)(at + brow * 128 + ((ks*64 + l4*16) ^ ((brow & 7) << 4)));
                acc[nt] = __builtin_amdgcn_mfma_f32_16x16x32_bf16(af, bf, acc[nt], 0, 0, 0);
            }
        }
        __syncthreads();
    }
    #undef LOADC
    if (!IN_BF16 && WRITE_SS){
        ss += __shfl_xor(ss, 1); ss += __shfl_xor(ss, 2);
        if (q4 == 0) sspart[sp * Mn + m0 + row] = ss;
    }
    #pragma unroll
    for (int nt = 0; nt < 4; ++nt)
        #pragma unroll
        for (int r = 0; r < 4; ++r){
            int ml = 16 * w + 4 * l4 + r;
            tpart[(size_t)sp * TSTRIDE + (size_t)(m0 + ml) * 64 + nt * 16 + lm] = acc[nt][r];
        }
}

// ---------------- stage t tile (sum 4 K-split partials, optional rms scale) into swizzled LDS
template<int DORMS>
__device__ __forceinline__ void stage_t(char* tt, const float* __restrict__ tpart,
                                        const float* __restrict__ sspart, int m0, int tid){
    int row = tid >> 2, q4 = tid & 3;
    const float* bp = tpart + (size_t)(m0 + row) * 64 + q4 * 16;
    float4 s[4];
    #pragma unroll
    for (int i = 0; i < 4; ++i){
        float4 a = ((const float4*)(bp + 0 * TSTRIDE))[i];
        float4 b = ((const float4*)(bp + 1 * TSTRIDE))[i];
        float4 c = ((const float4*)(bp + 2 * TSTRIDE))[i];
        float4 d = ((const float4*)(bp + 3 * TSTRIDE))[i];
        s[i] = make_float4(a.x+b.x+c.x+d.x, a.y+b.y+c.y+d.y, a.z+b.z+c.z+d.z, a.w+b.w+c.w+d.w);
    }
    float rr = 1.f;
    if (DORMS){
        int m = m0 + row;
        float ssum = sspart[m] + sspart[Mn + m] + sspart[2*Mn + m] + sspart[3*Mn + m];
        rr = rsqrtf(ssum * (1.f / 1024.f) + 1.1920929e-07f);
    }
    #pragma unroll
    for (int i = 0; i < 4; ++i){ s[i].x*=rr; s[i].y*=rr; s[i].z*=rr; s[i].w*=rr; }
    int swz = (row & 7) << 4;
    uint4 p0 = {pk2(s[0].x,s[0].y), pk2(s[0].z,s[0].w), pk2(s[1].x,s[1].y), pk2(s[1].z,s[1].w)};
    uint4 p1 = {pk2(s[2].x,s[2].y), pk2(s[2].z,s[2].w), pk2(s[3].x,s[3].y), pk2(s[3].z,s[3].w)};
    *(uint4*)(tt + row * 128 + ((q4 * 32) ^ swz)) = p0;
    *(uint4*)(tt + row * 128 + ((q4 * 32 + 16) ^ swz)) = p1;
}

// ---------------- up GEMM: out[m][n] = epi( sum_r t[m][r] * Bt[n][r] ), M-tile 32 x N-chunk 256
template<int SILU, int HASBASE, int OUT_BF16, int DORMS>
__global__ __launch_bounds__(256) void up_g(const float* __restrict__ tpart,
                                            const float* __restrict__ sspart,
                                            const unsigned short* __restrict__ Bt,
                                            const float* base,
                                            void* __restrict__ outp){
    __shared__ char tt[4096];
    __shared__ char bb[32768];
    int tid = threadIdx.x;
    int m0 = blockIdx.x * 32, n0 = blockIdx.y * 256;
    int w = tid >> 6, lane = tid & 63, l4 = lane >> 4, lm = lane & 15;
    int wm = w & 1, wn = w >> 1;
    if (tid < 128) stage_t<DORMS>(tt, tpart, sspart, m0, tid);
    {
        const uint4* s = (const uint4*)(Bt + (size_t)(n0 + tid) * 64);
        #pragma unroll
        for (int j = 0; j < 8; ++j){
            uint4 v = s[j];
            *(uint4*)(bb + tid * 128 + ((j * 16) ^ ((tid & 7) << 4))) = v;
        }
    }
    __syncthreads();
    bf16x8 af[2];
    #pragma unroll
    for (int ks = 0; ks < 2; ++ks){
        int arow = 16 * wm + lm;
        af[ks] = *(const bf16x8*)(tt + arow * 128 + ((ks*64 + l4*16) ^ ((arow & 7) << 4)));
    }
    f32x4 acc[8];
    #pragma unroll
    for (int nt = 0; nt < 8; ++nt) acc[nt] = (f32x4){0.f,0.f,0.f,0.f};
    #pragma unroll
    for (int nt = 0; nt < 8; ++nt){
        int brow = wn * 128 + nt * 16 + lm;
        #pragma unroll
        for (int ks = 0; ks < 2; ++ks){
            bf16x8 bf = *(const bf16x8*)(bb + brow * 128 + ((ks*64 + l4*16) ^ ((brow & 7) << 4)));
            acc[nt] = __builtin_amdgcn_mfma_f32_16x16x32_bf16(af[ks], bf, acc[nt], 0, 0, 0);
        }
    }
    #pragma unroll
    for (int nt = 0; nt < 8; ++nt)
        #pragma unroll
        for (int r = 0; r < 4; ++r){
            int m = m0 + 16 * wm + 4 * l4 + r;
            int n = n0 + wn * 128 + nt * 16 + lm;
            float v = acc[nt][r];
            if (SILU) v = v / (1.f + __expf(-v));
            if (HASBASE) v += base[(size_t)m * 1024 + n];
            if (OUT_BF16) ((unsigned short*)outp)[(size_t)m * 1024 + n] = f2bf(v);
            else          ((float*)outp)[(size_t)m * 1024 + n] = v;
        }
}

// ---------------- fused QKV up-proj + RoPE + V-transpose (t from partials, rms fused)
__global__ __launch_bounds__(256) void qkv_g(const float* __restrict__ tpart,
                                             const float* __restrict__ sspart,
                                             const unsigned short* __restrict__ Btq,
                                             const unsigned short* __restrict__ Btk,
                                             const unsigned short* __restrict__ Btv,
                                             const float2* __restrict__ rt,
                                             unsigned short* __restrict__ qout,
                                             unsigned short* __restrict__ kout,
                                             unsigned short* __restrict__ vtout){
    __shared__ char tt[8192];
    __shared__ char bb[32768];
    int tid = threadIdx.x;
    int m0 = blockIdx.x * 64, n0 = blockIdx.y * 256;
    int b = m0 >> 11, s0 = m0 & (Sn - 1);
    int h0 = n0 >> 7;
    int w = tid >> 6, lane = tid & 63, l4 = lane >> 4, lm = lane & 15;
    stage_t<1>(tt, tpart, sspart, m0, tid);
    #define STAGE_B(SRC) { const uint4* s = (const uint4*)((SRC) + (size_t)(n0 + tid) * 64); \
        _Pragma("unroll") for (int j = 0; j < 8; ++j){ uint4 v = s[j]; \
            *(uint4*)(bb + tid * 128 + ((j * 16) ^ ((tid & 7) << 4))) = v; } }
    STAGE_B(Btq);
    __syncthreads();
    bf16x8 af[2];
    #pragma unroll
    for (int ks = 0; ks < 2; ++ks){
        int arow = 16 * w + lm;
        af[ks] = *(const bf16x8*)(tt + arow * 128 + ((ks*64 + l4*16) ^ ((arow & 7) << 4)));
    }
    f32x4 acc[16];
    float2 cs[4][4];
    #pragma unroll
    for (int ntb = 0; ntb < 4; ++ntb)
        #pragma unroll
        for (int r = 0; r < 4; ++r)
            cs[ntb][r] = rt[(size_t)(s0 + 16*w + 4*l4 + r) * 64 + ntb * 16 + lm];

    #define MMUL() { _Pragma("unroll") for (int nt = 0; nt < 16; ++nt) acc[nt] = (f32x4){0.f,0.f,0.f,0.f}; \
        _Pragma("unroll") for (int nt = 0; nt < 16; ++nt){ int brow = nt * 16 + lm; \
            _Pragma("unroll") for (int ks = 0; ks < 2; ++ks){ \
                bf16x8 bf = *(const bf16x8*)(bb + brow * 128 + ((ks*64 + l4*16) ^ ((brow & 7) << 4))); \
                acc[nt] = __builtin_amdgcn_mfma_f32_16x16x32_bf16(af[ks], bf, acc[nt], 0, 0, 0); } } }

    #define ROPE() { _Pragma("unroll") for (int g = 0; g < 2; ++g) \
        _Pragma("unroll") for (int ntb = 0; ntb < 4; ++ntb){ int lo = g*8 + ntb, hi = lo + 4; \
            _Pragma("unroll") for (int r = 0; r < 4; ++r){ float2 c = cs[ntb][r]; \
                float a = acc[lo][r], bq = acc[hi][r]; \
                acc[lo][r] = a * c.x + bq * c.y; acc[hi][r] = -a * c.y + bq * c.x; } } }

    #define BOUNCE_STORE(DST) { \
        _Pragma("unroll") for (int nt = 0; nt < 16; ++nt) \
            _Pragma("unroll") for (int r = 0; r < 4; ++r){ \
                int nl = nt * 16 + lm, ml2 = 16 * w + 4 * l4 + r; \
                *(unsigned short*)(bb + ml2 * 512 + ((nl * 2) ^ ((ml2 & 7) << 4))) = f2bf(acc[nt][r]); } \
        __syncthreads(); \
        { int ml = tid >> 2, seg = tid & 3; \
          int head = h0 + (seg >> 1), hd0 = (seg & 1) * 64; \
          size_t dstbase = (((size_t)(b * 8 + head) * Sn + (s0 + ml)) * 128 + hd0); \
          _Pragma("unroll") for (int j = 0; j < 8; ++j){ \
              uint4 v = *(const uint4*)(bb + ml * 512 + ((seg * 128 + j * 16) ^ ((ml & 7) << 4))); \
              *(uint4*)((DST) + dstbase + j * 8) = v; } } \
        __syncthreads(); }

    MMUL(); ROPE();
    __syncthreads();
    BOUNCE_STORE(qout);
    STAGE_B(Btk);
    __syncthreads();
    MMUL(); ROPE();
    __syncthreads();
    BOUNCE_STORE(kout);
    STAGE_B(Btv);
    __syncthreads();
    MMUL();
    __syncthreads();
    #pragma unroll
    for (int nt = 0; nt < 16; ++nt)
        #pragma unroll
        for (int r = 0; r < 4; ++r){
            int nl = nt * 16 + lm, ml2 = 16 * w + 4 * l4 + r;
            *(unsigned short*)(bb + nl * 128 + ((ml2 * 2) ^ ((nl & 7) << 4))) = f2bf(acc[nt][r]);
        }
    __syncthreads();
    {
        int head = h0 + (tid >> 7), d = tid & 127;
        size_t dstbase = (((size_t)(b * 8 + head) * 128 + d) * Sn + s0);
        #pragma unroll
        for (int j = 0; j < 8; ++j){
            uint4 v = *(const uint4*)(bb + tid * 128 + ((j * 16) ^ ((tid & 7) << 4)));
            *(uint4*)(vtout + dstbase + j * 8) = v;
        }
    }
    #undef STAGE_B
    #undef MMUL
    #undef ROPE
    #undef BOUNCE_STORE
}

// ---------------- MFMA flash attention: paired q-tiles (j, 31-j), 8 waves, prefetch staging
#define KBASE 0
#define VBASE 16384
#define PBASE 32768
__global__ __launch_bounds__(512) void attn_kernel(const unsigned short* __restrict__ qb,
                                                   const unsigned short* __restrict__ kb,
                                                   const unsigned short* __restrict__ vtb,
                                                   float* __restrict__ y){
    __shared__ uint4 smem4[49152 / 16];
    char* smem = (char*)smem4;
    int bh = blockIdx.x;
    int pj = blockIdx.y;                    // pair index 0..15
    int b = bh >> 3, h = bh & 7;
    int tid = threadIdx.x;
    int w = tid >> 6, lane = tid & 63;
    int l4 = lane >> 4, lm = lane & 15;
    int wg = w >> 2, ws4 = w & 3;
    int q0 = (wg ? (31 - pj) : pj) * 64;
    int ntiles = 32 - pj;

    const unsigned short* qg = qb + ((size_t)bh * Sn + q0 + ws4 * 16 + lm) * HDn;
    bf16x8 qf[4];
    #pragma unroll
    for (int df = 0; df < 4; ++df)
        qf[df] = *(const bf16x8*)(qg + df * 32 + l4 * 8);

    f32x4 acc[8];
    #pragma unroll
    for (int dg = 0; dg < 8; ++dg) acc[dg] = (f32x4){0.f, 0.f, 0.f, 0.f};
    float mrun[4] = {-1e30f, -1e30f, -1e30f, -1e30f};
    float lrun[4] = {0.f, 0.f, 0.f, 0.f};

    const char* kgbase = (const char*)(kb + ((size_t)bh * Sn) * HDn);
    const char* vgbase = (const char*)(vtb + (size_t)bh * HDn * Sn);
    const float scale = 0.08838834764831845f;
    int wqmax = q0 + ws4 * 16 + 15;

    uint4 kr[2], vr[2];
    #define LOADT(T) { size_t j0b = (size_t)(T) * 64; \
        _Pragma("unroll") for (int p = 0; p < 2; ++p){ int c = tid + p * 512; \
            int krow = c >> 4, kcol = (c & 15) * 16; \
            kr[p] = *(const uint4*)(kgbase + (j0b + krow) * 256 + kcol); \
            int vrow = c >> 3, vcol = (c & 7) * 16; \
            vr[p] = *(const uint4*)(vgbase + (size_t)vrow * (Sn * 2) + j0b * 2 + vcol); } }

    LOADT(0);
    for (int t = 0; t < ntiles; ++t){
        #pragma unroll
        for (int p = 0; p < 2; ++p){
            int c = tid + p * 512;
            int krow = c >> 4, kcol = (c & 15) * 16;
            *(uint4*)(smem + KBASE + krow * 256 + (kcol ^ ((krow & 7) << 4))) = kr[p];
            int vrow = c >> 3, vcol = (c & 7) * 16;
            *(uint4*)(smem + VBASE + vrow * 128 + (vcol ^ ((vrow & 7) << 4))) = vr[p];
        }
        __syncthreads();
        if (t + 1 < ntiles) LOADT(t + 1);
        int j0 = t * 64;
        if (j0 <= wqmax){
            f32x4 sf[4];
            #pragma unroll
            for (int kc = 0; kc < 4; ++kc){
                sf[kc] = (f32x4){0.f, 0.f, 0.f, 0.f};
                #pragma unroll
                for (int df = 0; df < 4; ++df){
                    int krow = 16 * kc + lm;
                    bf16x8 kf = *(const bf16x8*)(smem + KBASE + krow * 256 +
                                  ((64 * df + 16 * l4) ^ ((krow & 7) << 4)));
                    sf[kc] = __builtin_amdgcn_mfma_f32_16x16x32_bf16(qf[df], kf, sf[kc], 0, 0, 0);
                }
            }
            float sv[4][4];
            #pragma unroll
            for (int kc = 0; kc < 4; ++kc){
                #pragma unroll
                for (int r = 0; r < 4; ++r){
                    float s = sf[kc][r] * scale;
                    int jc = j0 + 16 * kc + lm;
                    int qr = q0 + 16 * ws4 + 4 * l4 + r;
                    sv[kc][r] = (jc > qr) ? -1e30f : s;
                }
            }
            float cr[4];
            #pragma unroll
            for (int r = 0; r < 4; ++r){
                float mx = fmaxf(fmaxf(sv[0][r], sv[1][r]), fmaxf(sv[2][r], sv[3][r]));
                #pragma unroll
                for (int o = 8; o >= 1; o >>= 1) mx = fmaxf(mx, __shfl_xor(mx, o));
                float mnew = fmaxf(mrun[r], mx);
                cr[r] = __expf(mrun[r] - mnew);
                float ps = 0.f;
                #pragma unroll
                for (int kc = 0; kc < 4; ++kc){
                    float p = __expf(sv[kc][r] - mnew);
                    sv[kc][r] = p; ps += p;
                }
                #pragma unroll
                for (int o = 8; o >= 1; o >>= 1) ps += __shfl_xor(ps, o);
                lrun[r] = lrun[r] * cr[r] + ps;
                mrun[r] = mnew;
            }
            #pragma unroll
            for (int dg = 0; dg < 8; ++dg){
                acc[dg][0] *= cr[0]; acc[dg][1] *= cr[1];
                acc[dg][2] *= cr[2]; acc[dg][3] *= cr[3];
            }
            int pb = PBASE + w * 2048;
            #pragma unroll
            for (int kc = 0; kc < 4; ++kc){
                #pragma unroll
                for (int r = 0; r < 4; ++r){
                    int prow = 4 * l4 + r;
                    *(unsigned short*)(smem + pb + prow * 128 +
                        (((16 * kc + lm) * 2) ^ ((prow & 7) << 4))) = f2bf(sv[kc][r]);
                }
            }
            #pragma unroll
            for (int ks = 0; ks < 2; ++ks){
                bf16x8 pa = *(const bf16x8*)(smem + pb + lm * 128 +
                              ((64 * ks + 16 * l4) ^ ((lm & 7) << 4)));
                #pragma unroll
                for (int dg = 0; dg < 8; ++dg){
                    int vrow = 16 * dg + lm;
                    bf16x8 vf = *(const bf16x8*)(smem + VBASE + vrow * 128 +
                                  ((64 * ks + 16 * l4) ^ ((vrow & 7) << 4)));
                    acc[dg] = __builtin_amdgcn_mfma_f32_16x16x32_bf16(pa, vf, acc[dg], 0, 0, 0);
                }
            }
        }
        __syncthreads();
    }
    #undef LOADT
    #pragma unroll
    for (int r = 0; r < 4; ++r){
        float inv = 1.f / lrun[r];
        int qr = q0 + 16 * ws4 + 4 * l4 + r;
        float* yrow = y + ((size_t)b * Sn + qr) * Dn + h * HDn;
        #pragma unroll
        for (int dg = 0; dg < 8; ++dg)
            yrow[16 * dg + lm] = acc[dg][r] * inv;
    }
}

extern "C" void kernel_launch(void* const* d_in, const int* in_sizes, int n_in,
                              void* d_out, int out_size, void* d_ws, size_t ws_size,
                              hipStream_t stream){
    const float* x      = (const float*)d_in[0];
    const float* A      = (const float*)d_in[1];
    const float* Bm     = (const float*)d_in[2];
    const float* C_q    = (const float*)d_in[3];
    const float* C_k    = (const float*)d_in[4];
    const float* C_v    = (const float*)d_in[5];
    const float* C_o    = (const float*)d_in[6];
    const float* C_fc   = (const float*)d_in[7];
    const float* C_proj = (const float*)d_in[8];
    const float* scale1 = (const float*)d_in[9];
    const float* scale2 = (const float*)d_in[10];
    float* out = (float*)d_out;

    char* ws = (char*)d_ws;
    size_t off = 0;
    auto alloc = [&](size_t bytes)->char*{ char* p = ws + off; off += (bytes + 255) & ~(size_t)255; return p; };
    unsigned short* qb   = (unsigned short*)alloc((size_t)Mn * Dn * 2);   // 8MB
    unsigned short* kb   = (unsigned short*)alloc((size_t)Mn * Dn * 2);   // 8MB
    unsigned short* vtb  = (unsigned short*)alloc((size_t)Mn * Dn * 2);   // 8MB
    float*          y    = (float*)alloc((size_t)Mn * Dn * 4);            // 16MB
    float*          tp   = (float*)alloc(4 * TSTRIDE * 4);                // 4MB  (4 K-splits)
    float*          ssp  = (float*)alloc(4 * (size_t)Mn * 4);             // 64KB
    unsigned short* At0  = (unsigned short*)alloc(65536 * 2);
    unsigned short* At1  = (unsigned short*)alloc(65536 * 2);
    unsigned short* At2  = (unsigned short*)alloc(65536 * 2);
    unsigned short* Btq  = (unsigned short*)alloc(65536 * 2);
    unsigned short* Btk  = (unsigned short*)alloc(65536 * 2);
    unsigned short* Btv  = (unsigned short*)alloc(65536 * 2);
    unsigned short* Bto  = (unsigned short*)alloc(65536 * 2);
    unsigned short* Btfc = (unsigned short*)alloc(65536 * 2);
    unsigned short* Btpr = (unsigned short*)alloc(65536 * 2);
    float2*         rt   = (float2*)alloc((size_t)Sn * 64 * 8);           // 1MB
    unsigned short* mb   = qb;  // overlay: q dead after attention

    prep_g<<<2816, 256, 0, stream>>>(A, Bm, C_q, C_k, C_v, C_o, C_fc, C_proj,
                                     scale1, scale2, At0, At1, At2,
                                     Btq, Btk, Btv, Bto, Btfc, Btpr, rt);
    // t1 partials = x @ At1 (s1 folded), ss = rowwise sumsq(x)
    down_g<0, 1><<<dim3(Mn / 64, 4), 256, 0, stream>>>(x, At1, tp, ssp);
    // q,k (roped) + v^T ; rms applied during t-staging
    qkv_g<<<dim3(Mn / 64, 4), 256, 0, stream>>>(tp, ssp, Btq, Btk, Btv, rt, qb, kb, vtb);
    // attention (paired tiles)
    attn_kernel<<<dim3(Bn * Hn, 16), 512, 0, stream>>>(qb, kb, vtb, y);
    // t2 partials = y @ At0
    down_g<0, 0><<<dim3(Mn / 64, 4), 256, 0, stream>>>(y, At0, tp, nullptr);
    // x1 = x + t2 @ Bto
    up_g<0, 1, 0, 0><<<dim3(Mn / 32, 4), 256, 0, stream>>>(tp, nullptr, Bto, x, out);
    // t3 partials = x1 @ At2 (s2 folded), ss = sumsq(x1)
    down_g<0, 1><<<dim3(Mn / 64, 4), 256, 0, stream>>>(out, At2, tp, ssp);
    // mb = silu(rms-scaled t3 @ Btfc)  (bf16)
    up_g<1, 0, 1, 1><<<dim3(Mn / 32, 4), 256, 0, stream>>>(tp, ssp, Btfc, nullptr, mb);
    // t4 partials = mb @ At0
    down_g<1, 0><<<dim3(Mn / 64, 4), 256, 0, stream>>>(mb, At0, tp, nullptr);
    // out = x1 + t4 @ Btpr
    up_g<0, 1, 0, 0><<<dim3(Mn / 32, 4), 256, 0, stream>>>(tp, nullptr, Btpr, out, out);
}

// Round 5
// 202.920 us; speedup vs baseline: 11.3279x; 1.0540x over previous
//
#include <hip/hip_runtime.h>

// HolographicBlock: B=2, S=2048, D=1024, R=64, H=8, HD=128
// Projections = bf16 MFMA GEMMs (K-split down-proj, f32 partials).
// Attention = K-split flash attention: 128-row q-tiles, 32 rows/wave,
// pre-swizzled K/V tile images, LDS double-buffer, 1 barrier/iter, combine pass.

#define Bn 2
#define Sn 2048
#define Dn 1024
#define Rn 64
#define Hn 8
#define HDn 128
#define Mn (Bn*Sn)   // 4096 rows
#define TSTRIDE ((size_t)Mn * Rn)

typedef __bf16 bf16x8 __attribute__((ext_vector_type(8)));
typedef float f32x4 __attribute__((ext_vector_type(4)));

__device__ __forceinline__ float bf2f(unsigned short u){
    union { unsigned int i; float f; } x; x.i = ((unsigned int)u) << 16; return x.f;
}
__device__ __forceinline__ unsigned short f2bf(float f){
    union { float f; unsigned int i; } x; x.f = f;
    unsigned int r = x.i + 0x7fffu + ((x.i >> 16) & 1u);
    return (unsigned short)(r >> 16);
}
__device__ __forceinline__ unsigned int pk2(float a, float b){
    return (unsigned int)f2bf(a) | ((unsigned int)f2bf(b) << 16);
}

// ---------------- prep: bf16 transposed weights + rope table
__global__ __launch_bounds__(256) void prep_g(const float* __restrict__ A,
                                              const float* __restrict__ Bsrc,
                                              const float* __restrict__ Cq, const float* __restrict__ Ck,
                                              const float* __restrict__ Cv, const float* __restrict__ Co,
                                              const float* __restrict__ Cfc, const float* __restrict__ Cpr,
                                              const float* __restrict__ s1, const float* __restrict__ s2,
                                              unsigned short* __restrict__ At0, unsigned short* __restrict__ At1,
                                              unsigned short* __restrict__ At2,
                                              unsigned short* __restrict__ Btq, unsigned short* __restrict__ Btk,
                                              unsigned short* __restrict__ Btv, unsigned short* __restrict__ Bto,
                                              unsigned short* __restrict__ Btfc, unsigned short* __restrict__ Btpr,
                                              float2* __restrict__ rt){
    int idx = blockIdx.x * 256 + threadIdx.x;
    if (idx < 3 * 65536){
        int v = idx >> 16, e = idx & 65535;
        int r = e >> 10, d = e & 1023;
        float sc = (v == 0) ? 1.f : (v == 1 ? s1[d] : s2[d]);
        unsigned short val = f2bf(A[d * 64 + r] * sc);
        (v == 0 ? At0 : v == 1 ? At1 : At2)[e] = val;
    } else if (idx < 9 * 65536){
        int v = (idx - 3 * 65536) >> 16, e = idx & 65535;
        int d = e >> 6, r = e & 63;
        const float* C = v==0?Cq : v==1?Ck : v==2?Cv : v==3?Co : v==4?Cfc : Cpr;
        unsigned short val = f2bf(Bsrc[r * 1024 + d] * C[r]);
        (v==0?Btq : v==1?Btk : v==2?Btv : v==3?Bto : v==4?Btfc : Btpr)[e] = val;
    } else if (idx < 9 * 65536 + Sn * 64){
        int e = idx - 9 * 65536;
        int s = e >> 6, f = e & 63;
        float inv = exp2f(-(float)f * (13.287712379549449f / 64.0f));
        float fr = (float)s * inv;
        float sn, cs; sincosf(fr, &sn, &cs);
        rt[e] = make_float2(cs, sn);
    }
}

// ---------------- down GEMM (K-split): tpart[sp][m][r] = sum_{d in split} in[m][d] * At[r][d]
template<int IN_BF16, int WRITE_SS>
__global__ __launch_bounds__(256) void down_g(const void* __restrict__ inp,
                                              const unsigned short* __restrict__ At,
                                              float* __restrict__ tpart,
                                              float* __restrict__ sspart){
    __shared__ char xt[8192];
    __shared__ char at[8192];
    int tid = threadIdx.x;
    int m0 = blockIdx.x * 64, sp = blockIdx.y;
    int row = tid >> 2, q4 = tid & 3;
    int w = tid >> 6, lane = tid & 63, l4 = lane >> 4, lm = lane & 15;
    int swz = (row & 7) << 4;
    float ss = 0.f;
    f32x4 acc[4];
    #pragma unroll
    for (int nt = 0; nt < 4; ++nt) acc[nt] = (f32x4){0.f,0.f,0.f,0.f};

    float4 xr[4]; uint4 xrb[2]; uint4 ar[2];
    #define LOADC(c) { int k0 = sp * 256 + (c) * 64; \
        if (!IN_BF16){ const float4* s = (const float4*)((const float*)inp + (size_t)(m0+row)*1024 + k0 + q4*16); \
            xr[0]=s[0]; xr[1]=s[1]; xr[2]=s[2]; xr[3]=s[3]; } \
        else { const uint4* s = (const uint4*)((const unsigned short*)inp + (size_t)(m0+row)*1024 + k0 + q4*16); \
            xrb[0]=s[0]; xrb[1]=s[1]; } \
        const uint4* a = (const uint4*)(At + (size_t)row*1024 + k0 + q4*16); \
        ar[0]=a[0]; ar[1]=a[1]; }

    LOADC(0);
    for (int c = 0; c < 4; ++c){
        int b0 = row * 128 + ((q4 * 32) ^ swz);
        int b1 = row * 128 + ((q4 * 32 + 16) ^ swz);
        if (!IN_BF16){
            if (WRITE_SS){
                #pragma unroll
                for (int i = 0; i < 4; ++i)
                    ss += xr[i].x*xr[i].x + xr[i].y*xr[i].y + xr[i].z*xr[i].z + xr[i].w*xr[i].w;
            }
            uint4 p0 = {pk2(xr[0].x,xr[0].y), pk2(xr[0].z,xr[0].w), pk2(xr[1].x,xr[1].y), pk2(xr[1].z,xr[1].w)};
            uint4 p1 = {pk2(xr[2].x,xr[2].y), pk2(xr[2].z,xr[2].w), pk2(xr[3].x,xr[3].y), pk2(xr[3].z,xr[3].w)};
            *(uint4*)(xt + b0) = p0; *(uint4*)(xt + b1) = p1;
        } else {
            *(uint4*)(xt + b0) = xrb[0]; *(uint4*)(xt + b1) = xrb[1];
        }
        *(uint4*)(at + b0) = ar[0]; *(uint4*)(at + b1) = ar[1];
        __syncthreads();
        if (c < 3) LOADC(c + 1);
        #pragma unroll
        for (int ks = 0; ks < 2; ++ks){
            int arow = 16 * w + lm;
            bf16x8 af = *(const bf16x8*)(xt + arow * 128 + ((ks*64 + l4*16) ^ ((arow & 7) << 4)));
            #pragma unroll
            for (int nt = 0; nt < 4; ++nt){
                int brow = nt * 16 + lm;
                bf16x8 bf = *(const bf16x8*)(at + brow * 128 + ((ks*64 + l4*16) ^ ((brow & 7) << 4)));
                acc[nt] = __builtin_amdgcn_mfma_f32_16x16x32_bf16(af, bf, acc[nt], 0, 0, 0);
            }
        }
        __syncthreads();
    }
    #undef LOADC
    if (!IN_BF16 && WRITE_SS){
        ss += __shfl_xor(ss, 1); ss += __shfl_xor(ss, 2);
        if (q4 == 0) sspart[sp * Mn + m0 + row] = ss;
    }
    #pragma unroll
    for (int nt = 0; nt < 4; ++nt)
        #pragma unroll
        for (int r = 0; r < 4; ++r){
            int ml = 16 * w + 4 * l4 + r;
            tpart[(size_t)sp * TSTRIDE + (size_t)(m0 + ml) * 64 + nt * 16 + lm] = acc[nt][r];
        }
}

// ---------------- stage t tile (sum 4 K-split partials, optional rms scale) into swizzled LDS
template<int DORMS>
__device__ __forceinline__ void stage_t(char* tt, const float* __restrict__ tpart,
                                        const float* __restrict__ sspart, int m0, int tid){
    int row = tid >> 2, q4 = tid & 3;
    const float* bp = tpart + (size_t)(m0 + row) * 64 + q4 * 16;
    float4 s[4];
    #pragma unroll
    for (int i = 0; i < 4; ++i){
        float4 a = ((const float4*)(bp + 0 * TSTRIDE))[i];
        float4 b = ((const float4*)(bp + 1 * TSTRIDE))[i];
        float4 c = ((const float4*)(bp + 2 * TSTRIDE))[i];
        float4 d = ((const float4*)(bp + 3 * TSTRIDE))[i];
        s[i] = make_float4(a.x+b.x+c.x+d.x, a.y+b.y+c.y+d.y, a.z+b.z+c.z+d.z, a.w+b.w+c.w+d.w);
    }
    float rr = 1.f;
    if (DORMS){
        int m = m0 + row;
        float ssum = sspart[m] + sspart[Mn + m] + sspart[2*Mn + m] + sspart[3*Mn + m];
        rr = rsqrtf(ssum * (1.f / 1024.f) + 1.1920929e-07f);
    }
    #pragma unroll
    for (int i = 0; i < 4; ++i){ s[i].x*=rr; s[i].y*=rr; s[i].z*=rr; s[i].w*=rr; }
    int swz = (row & 7) << 4;
    uint4 p0 = {pk2(s[0].x,s[0].y), pk2(s[0].z,s[0].w), pk2(s[1].x,s[1].y), pk2(s[1].z,s[1].w)};
    uint4 p1 = {pk2(s[2].x,s[2].y), pk2(s[2].z,s[2].w), pk2(s[3].x,s[3].y), pk2(s[3].z,s[3].w)};
    *(uint4*)(tt + row * 128 + ((q4 * 32) ^ swz)) = p0;
    *(uint4*)(tt + row * 128 + ((q4 * 32 + 16) ^ swz)) = p1;
}

// ---------------- up GEMM: M-tile 32 x N-chunk 256, K=64
template<int SILU, int HASBASE, int OUT_BF16, int DORMS>
__global__ __launch_bounds__(256) void up_g(const float* __restrict__ tpart,
                                            const float* __restrict__ sspart,
                                            const unsigned short* __restrict__ Bt,
                                            const float* base,
                                            void* __restrict__ outp){
    __shared__ char tt[4096];
    __shared__ char bb[32768];
    int tid = threadIdx.x;
    int m0 = blockIdx.x * 32, n0 = blockIdx.y * 256;
    int w = tid >> 6, lane = tid & 63, l4 = lane >> 4, lm = lane & 15;
    int wm = w & 1, wn = w >> 1;
    if (tid < 128) stage_t<DORMS>(tt, tpart, sspart, m0, tid);
    {
        const uint4* s = (const uint4*)(Bt + (size_t)(n0 + tid) * 64);
        #pragma unroll
        for (int j = 0; j < 8; ++j){
            uint4 v = s[j];
            *(uint4*)(bb + tid * 128 + ((j * 16) ^ ((tid & 7) << 4))) = v;
        }
    }
    __syncthreads();
    bf16x8 af[2];
    #pragma unroll
    for (int ks = 0; ks < 2; ++ks){
        int arow = 16 * wm + lm;
        af[ks] = *(const bf16x8*)(tt + arow * 128 + ((ks*64 + l4*16) ^ ((arow & 7) << 4)));
    }
    f32x4 acc[8];
    #pragma unroll
    for (int nt = 0; nt < 8; ++nt) acc[nt] = (f32x4){0.f,0.f,0.f,0.f};
    #pragma unroll
    for (int nt = 0; nt < 8; ++nt){
        int brow = wn * 128 + nt * 16 + lm;
        #pragma unroll
        for (int ks = 0; ks < 2; ++ks){
            bf16x8 bf = *(const bf16x8*)(bb + brow * 128 + ((ks*64 + l4*16) ^ ((brow & 7) << 4)));
            acc[nt] = __builtin_amdgcn_mfma_f32_16x16x32_bf16(af[ks], bf, acc[nt], 0, 0, 0);
        }
    }
    #pragma unroll
    for (int nt = 0; nt < 8; ++nt)
        #pragma unroll
        for (int r = 0; r < 4; ++r){
            int m = m0 + 16 * wm + 4 * l4 + r;
            int n = n0 + wn * 128 + nt * 16 + lm;
            float v = acc[nt][r];
            if (SILU) v = v / (1.f + __expf(-v));
            if (HASBASE) v += base[(size_t)m * 1024 + n];
            if (OUT_BF16) ((unsigned short*)outp)[(size_t)m * 1024 + n] = f2bf(v);
            else          ((float*)outp)[(size_t)m * 1024 + n] = v;
        }
}

// ---------------- fused QKV up-proj + RoPE; K,V written as pre-swizzled tile images
// Kimg: [bh][tile32][row64][256B swz]; Vimg: [bh][tile32][d128][128B swz]
__global__ __launch_bounds__(256) void qkv_g(const float* __restrict__ tpart,
                                             const float* __restrict__ sspart,
                                             const unsigned short* __restrict__ Btq,
                                             const unsigned short* __restrict__ Btk,
                                             const unsigned short* __restrict__ Btv,
                                             const float2* __restrict__ rt,
                                             unsigned short* __restrict__ qout,
                                             char* __restrict__ Kimg,
                                             char* __restrict__ Vimg){
    __shared__ char tt[8192];
    __shared__ char bb[32768];
    int tid = threadIdx.x;
    int m0 = blockIdx.x * 64, n0 = blockIdx.y * 256;
    int b = m0 >> 11, s0 = m0 & (Sn - 1);
    int h0 = n0 >> 7;
    int w = tid >> 6, lane = tid & 63, l4 = lane >> 4, lm = lane & 15;
    stage_t<1>(tt, tpart, sspart, m0, tid);
    #define STAGE_B(SRC) { const uint4* s = (const uint4*)((SRC) + (size_t)(n0 + tid) * 64); \
        _Pragma("unroll") for (int j = 0; j < 8; ++j){ uint4 v = s[j]; \
            *(uint4*)(bb + tid * 128 + ((j * 16) ^ ((tid & 7) << 4))) = v; } }
    STAGE_B(Btq);
    __syncthreads();
    bf16x8 af[2];
    #pragma unroll
    for (int ks = 0; ks < 2; ++ks){
        int arow = 16 * w + lm;
        af[ks] = *(const bf16x8*)(tt + arow * 128 + ((ks*64 + l4*16) ^ ((arow & 7) << 4)));
    }
    f32x4 acc[16];
    float2 cs[4][4];
    #pragma unroll
    for (int ntb = 0; ntb < 4; ++ntb)
        #pragma unroll
        for (int r = 0; r < 4; ++r)
            cs[ntb][r] = rt[(size_t)(s0 + 16*w + 4*l4 + r) * 64 + ntb * 16 + lm];

    #define MMUL() { _Pragma("unroll") for (int nt = 0; nt < 16; ++nt) acc[nt] = (f32x4){0.f,0.f,0.f,0.f}; \
        _Pragma("unroll") for (int nt = 0; nt < 16; ++nt){ int brow = nt * 16 + lm; \
            _Pragma("unroll") for (int ks = 0; ks < 2; ++ks){ \
                bf16x8 bf = *(const bf16x8*)(bb + brow * 128 + ((ks*64 + l4*16) ^ ((brow & 7) << 4))); \
                acc[nt] = __builtin_amdgcn_mfma_f32_16x16x32_bf16(af[ks], bf, acc[nt], 0, 0, 0); } } }

    #define ROPE() { _Pragma("unroll") for (int g = 0; g < 2; ++g) \
        _Pragma("unroll") for (int ntb = 0; ntb < 4; ++ntb){ int lo = g*8 + ntb, hi = lo + 4; \
            _Pragma("unroll") for (int r = 0; r < 4; ++r){ float2 c = cs[ntb][r]; \
                float a = acc[lo][r], bq = acc[hi][r]; \
                acc[lo][r] = a * c.x + bq * c.y; acc[hi][r] = -a * c.y + bq * c.x; } } }

    #define BOUNCE() { \
        _Pragma("unroll") for (int nt = 0; nt < 16; ++nt) \
            _Pragma("unroll") for (int r = 0; r < 4; ++r){ \
                int nl = nt * 16 + lm, ml2 = 16 * w + 4 * l4 + r; \
                *(unsigned short*)(bb + ml2 * 512 + ((nl * 2) ^ ((ml2 & 7) << 4))) = f2bf(acc[nt][r]); } \
        __syncthreads(); }

    // ---- Q -> [bh,s,hd]
    MMUL(); ROPE();
    __syncthreads();
    BOUNCE();
    {
        int ml = tid >> 2, seg = tid & 3;
        int head = h0 + (seg >> 1), hd0q = (seg & 1) * 64;
        size_t dstbase = (((size_t)(b * 8 + head) * Sn + (s0 + ml)) * 128 + hd0q);
        #pragma unroll
        for (int j = 0; j < 8; ++j){
            uint4 v = *(const uint4*)(bb + ml * 512 + ((seg * 128 + j * 16) ^ ((ml & 7) << 4)));
            *(uint4*)(qout + dstbase + j * 8) = v;
        }
    }
    __syncthreads();
    // ---- K -> swizzled tile image
    STAGE_B(Btk);
    __syncthreads();
    MMUL(); ROPE();
    __syncthreads();
    BOUNCE();
    {
        int ml = tid >> 2, seg = tid & 3;
        int head = h0 + (seg >> 1), hd0q = (seg & 1) * 64;
        size_t rowb = (((size_t)(b * 8 + head) * 32 + (s0 >> 6)) * 64 + ml) * 256;
        #pragma unroll
        for (int j = 0; j < 8; ++j){
            uint4 v = *(const uint4*)(bb + ml * 512 + ((seg * 128 + j * 16) ^ ((ml & 7) << 4)));
            int cb = hd0q * 2 + j * 16;
            *(uint4*)(Kimg + rowb + (cb ^ ((ml & 7) << 4))) = v;
        }
    }
    __syncthreads();
    // ---- V -> transposed swizzled tile image
    STAGE_B(Btv);
    __syncthreads();
    MMUL();
    __syncthreads();
    #pragma unroll
    for (int nt = 0; nt < 16; ++nt)
        #pragma unroll
        for (int r = 0; r < 4; ++r){
            int nl = nt * 16 + lm, ml2 = 16 * w + 4 * l4 + r;
            *(unsigned short*)(bb + nl * 128 + ((ml2 * 2) ^ ((nl & 7) << 4))) = f2bf(acc[nt][r]);
        }
    __syncthreads();
    {
        int head = h0 + (tid >> 7), d = tid & 127;
        size_t rowb = (((size_t)(b * 8 + head) * 32 + (s0 >> 6)) * 128 + d) * 128;
        #pragma unroll
        for (int j = 0; j < 8; ++j){
            uint4 v = *(const uint4*)(bb + tid * 128 + ((j * 16) ^ ((tid & 7) << 4)));
            *(uint4*)(Vimg + rowb + ((j * 16) ^ ((d & 7) << 4))) = v;
        }
    }
    #undef STAGE_B
    #undef MMUL
    #undef ROPE
    #undef BOUNCE
}

// ---------------- K-split flash attention
// 384 blocks: grp0: (J=8+g, slice0, 16 tiles); grp1: (J=15-g, slice1, 2J-14 tiles);
// grp2: (J=7-g, direct, 2J+2 tiles). 4 waves, 32 q-rows/wave.
__global__ __launch_bounds__(256, 2) void attn2_kernel(const unsigned short* __restrict__ qb,
                                                       const char* __restrict__ Kimg,
                                                       const char* __restrict__ Vimg,
                                                       unsigned short* __restrict__ ybf,
                                                       float* __restrict__ pacc,
                                                       float2* __restrict__ pml){
    __shared__ uint4 smem4[81920 / 16];
    char* smem = (char*)smem4;
    int tid = threadIdx.x;
    int w = tid >> 6, lane = tid & 63, l4 = lane >> 4, lm = lane & 15;
    int id = blockIdx.x;
    int grp = id >> 7, wi = id & 127;
    int bh = wi & 15, g = wi >> 4;
    int J, t0, niters, direct, slice;
    if (grp == 0){ J = 8 + g;  t0 = 0;  niters = 16;         direct = 0; slice = (bh * 8 + g) * 2; }
    else if (grp == 1){ J = 15 - g; t0 = 16; niters = 2 * J - 14; direct = 0; slice = (bh * 8 + (J - 8)) * 2 + 1; }
    else { J = 7 - g;  t0 = 0;  niters = 2 * J + 2;  direct = 1; slice = 0; }
    int b = bh >> 3, h = bh & 7;
    int qrow0w = 128 * J + 32 * w;
    int wqmax = qrow0w + 31;

    bf16x8 qf[2][4];
    #pragma unroll
    for (int f = 0; f < 2; ++f){
        const unsigned short* qg = qb + ((size_t)bh * Sn + qrow0w + 16 * f + lm) * HDn;
        #pragma unroll
        for (int df = 0; df < 4; ++df)
            qf[f][df] = *(const bf16x8*)(qg + df * 32 + l4 * 8);
    }
    f32x4 acc[2][8];
    #pragma unroll
    for (int f = 0; f < 2; ++f)
        #pragma unroll
        for (int dg = 0; dg < 8; ++dg) acc[f][dg] = (f32x4){0.f,0.f,0.f,0.f};
    float mrun[2][4], lrun[2][4];
    #pragma unroll
    for (int f = 0; f < 2; ++f)
        #pragma unroll
        for (int r = 0; r < 4; ++r){ mrun[f][r] = -1e30f; lrun[f][r] = 0.f; }

    const float scale = 0.08838834764831845f;
    size_t imgbase = (size_t)bh * 32 * 16384;

    uint4 sk[4], sv4[4];
    {   // prologue: stage t0 -> buf0
        size_t tb = imgbase + (size_t)t0 * 16384;
        #pragma unroll
        for (int i = 0; i < 4; ++i){
            sk[i]  = *(const uint4*)(Kimg + tb + i * 4096 + tid * 16);
            sv4[i] = *(const uint4*)(Vimg + tb + i * 4096 + tid * 16);
        }
        #pragma unroll
        for (int i = 0; i < 4; ++i){
            *(uint4*)(smem + i * 4096 + tid * 16) = sk[i];
            *(uint4*)(smem + 16384 + i * 4096 + tid * 16) = sv4[i];
        }
    }
    __syncthreads();

    for (int it = 0; it < niters; ++it){
        int t = t0 + it;
        int bsel = (it & 1) << 15;
        if (it + 1 < niters){
            size_t tb = imgbase + (size_t)(t + 1) * 16384;
            #pragma unroll
            for (int i = 0; i < 4; ++i){
                sk[i]  = *(const uint4*)(Kimg + tb + i * 4096 + tid * 16);
                sv4[i] = *(const uint4*)(Vimg + tb + i * 4096 + tid * 16);
            }
        }
        if (64 * t <= wqmax){
            char* KL = smem + bsel;
            char* VL = smem + bsel + 16384;
            char* pb = smem + 65536 + (w << 12);
            f32x4 sf[2][4];
            #pragma unroll
            for (int kc = 0; kc < 4; ++kc){ sf[0][kc] = (f32x4){0.f,0.f,0.f,0.f}; sf[1][kc] = (f32x4){0.f,0.f,0.f,0.f}; }
            #pragma unroll
            for (int kc = 0; kc < 4; ++kc){
                int krow = 16 * kc + lm;
                int ksw = (krow & 7) << 4;
                #pragma unroll
                for (int df = 0; df < 4; ++df){
                    bf16x8 kf = *(const bf16x8*)(KL + krow * 256 + ((df * 64 + l4 * 16) ^ ksw));
                    sf[0][kc] = __builtin_amdgcn_mfma_f32_16x16x32_bf16(qf[0][df], kf, sf[0][kc], 0, 0, 0);
                    sf[1][kc] = __builtin_amdgcn_mfma_f32_16x16x32_bf16(qf[1][df], kf, sf[1][kc], 0, 0, 0);
                }
            }
            bool needmask = (64 * t + 63 > qrow0w);
            float cr[2][4];
            #pragma unroll
            for (int f = 0; f < 2; ++f){
                #pragma unroll
                for (int r = 0; r < 4; ++r){
                    float s0v = sf[f][0][r] * scale, s1v = sf[f][1][r] * scale,
                          s2v = sf[f][2][r] * scale, s3v = sf[f][3][r] * scale;
                    if (needmask){
                        int qr = qrow0w + 16 * f + 4 * l4 + r;
                        int j0k = 64 * t + lm;
                        s0v = (j0k      > qr) ? -1e30f : s0v;
                        s1v = (j0k + 16 > qr) ? -1e30f : s1v;
                        s2v = (j0k + 32 > qr) ? -1e30f : s2v;
                        s3v = (j0k + 48 > qr) ? -1e30f : s3v;
                    }
                    float mx = fmaxf(fmaxf(s0v, s1v), fmaxf(s2v, s3v));
                    #pragma unroll
                    for (int o = 8; o >= 1; o >>= 1) mx = fmaxf(mx, __shfl_xor(mx, o));
                    float mnew = fmaxf(mrun[f][r], mx);
                    float c = __expf(mrun[f][r] - mnew);
                    float p0 = __expf(s0v - mnew), p1 = __expf(s1v - mnew),
                          p2 = __expf(s2v - mnew), p3 = __expf(s3v - mnew);
                    float ps = p0 + p1 + p2 + p3;
                    #pragma unroll
                    for (int o = 8; o >= 1; o >>= 1) ps += __shfl_xor(ps, o);
                    lrun[f][r] = lrun[f][r] * c + ps;
                    mrun[f][r] = mnew;
                    cr[f][r] = c;
                    int prow = 16 * f + 4 * l4 + r;
                    int psw = (prow & 7) << 4;
                    char* pr = pb + prow * 128;
                    *(unsigned short*)(pr + ((lm * 2     ) ^ psw)) = f2bf(p0);
                    *(unsigned short*)(pr + ((lm * 2 + 32) ^ psw)) = f2bf(p1);
                    *(unsigned short*)(pr + ((lm * 2 + 64) ^ psw)) = f2bf(p2);
                    *(unsigned short*)(pr + ((lm * 2 + 96) ^ psw)) = f2bf(p3);
                }
            }
            #pragma unroll
            for (int f = 0; f < 2; ++f)
                #pragma unroll
                for (int dg = 0; dg < 8; ++dg){
                    acc[f][dg][0] *= cr[f][0]; acc[f][dg][1] *= cr[f][1];
                    acc[f][dg][2] *= cr[f][2]; acc[f][dg][3] *= cr[f][3];
                }
            #pragma unroll
            for (int ks = 0; ks < 2; ++ks){
                int pcol = (ks * 64 + l4 * 16) ^ ((lm & 7) << 4);
                bf16x8 pa0 = *(const bf16x8*)(pb + lm * 128 + pcol);
                bf16x8 pa1 = *(const bf16x8*)(pb + (16 + lm) * 128 + pcol);
                #pragma unroll
                for (int dg = 0; dg < 8; ++dg){
                    int vrow = 16 * dg + lm;
                    bf16x8 vf = *(const bf16x8*)(VL + vrow * 128 + ((ks * 64 + l4 * 16) ^ ((vrow & 7) << 4)));
                    acc[0][dg] = __builtin_amdgcn_mfma_f32_16x16x32_bf16(pa0, vf, acc[0][dg], 0, 0, 0);
                    acc[1][dg] = __builtin_amdgcn_mfma_f32_16x16x32_bf16(pa1, vf, acc[1][dg], 0, 0, 0);
                }
            }
        }
        if (it + 1 < niters){
            int ob = bsel ^ 32768;
            #pragma unroll
            for (int i = 0; i < 4; ++i){
                *(uint4*)(smem + ob + i * 4096 + tid * 16) = sk[i];
                *(uint4*)(smem + ob + 16384 + i * 4096 + tid * 16) = sv4[i];
            }
        }
        __syncthreads();
    }
    if (direct){
        #pragma unroll
        for (int f = 0; f < 2; ++f)
            #pragma unroll
            for (int r = 0; r < 4; ++r){
                float inv = 1.f / lrun[f][r];
                int row = qrow0w + 16 * f + 4 * l4 + r;
                unsigned short* yr = ybf + ((size_t)b * Sn + row) * Dn + h * HDn;
                #pragma unroll
                for (int dg = 0; dg < 8; ++dg)
                    yr[16 * dg + lm] = f2bf(acc[f][dg][r] * inv);
            }
    } else {
        float* pa_ = pacc + (size_t)slice * 16384;
        #pragma unroll
        for (int f = 0; f < 2; ++f)
            #pragma unroll
            for (int r = 0; r < 4; ++r){
                int row = 32 * w + 16 * f + 4 * l4 + r;
                #pragma unroll
                for (int dg = 0; dg < 8; ++dg)
                    pa_[row * 128 + 16 * dg + lm] = acc[f][dg][r];
                if (lm == 0)
                    pml[slice * 128 + row] = make_float2(mrun[f][r], lrun[f][r]);
            }
    }
}

// ---------------- combine two K-slices -> y (bf16)
__global__ __launch_bounds__(256) void comb_g(const float* __restrict__ pacc,
                                              const float2* __restrict__ pml,
                                              unsigned short* __restrict__ ybf){
    int bh = blockIdx.x >> 3, g = blockIdx.x & 7, J = 8 + g;
    int s0 = (bh * 8 + g) * 2, s1 = s0 + 1;
    int tid = threadIdx.x;
    __shared__ float w0s[128], w1s[128];
    if (tid < 128){
        float2 a = pml[s0 * 128 + tid], bq = pml[s1 * 128 + tid];
        float M = fmaxf(a.x, bq.x);
        float c0 = __expf(a.x - M), c1 = __expf(bq.x - M);
        float inv = 1.f / (c0 * a.y + c1 * bq.y);
        w0s[tid] = c0 * inv; w1s[tid] = c1 * inv;
    }
    __syncthreads();
    int b = bh >> 3, h = bh & 7;
    const float4* p0 = (const float4*)(pacc + (size_t)s0 * 16384);
    const float4* p1 = (const float4*)(pacc + (size_t)s1 * 16384);
    #pragma unroll
    for (int i = 0; i < 16; ++i){
        int idx = i * 256 + tid;
        int row = idx >> 5, c4 = idx & 31;
        float4 a0 = p0[idx], a1 = p1[idx];
        float W0 = w0s[row], W1 = w1s[row];
        ushort4 o;
        o.x = f2bf(a0.x * W0 + a1.x * W1);
        o.y = f2bf(a0.y * W0 + a1.y * W1);
        o.z = f2bf(a0.z * W0 + a1.z * W1);
        o.w = f2bf(a0.w * W0 + a1.w * W1);
        int srow = 128 * J + row;
        *(ushort4*)(ybf + ((size_t)b * Sn + srow) * Dn + h * HDn + c4 * 4) = o;
    }
}

extern "C" void kernel_launch(void* const* d_in, const int* in_sizes, int n_in,
                              void* d_out, int out_size, void* d_ws, size_t ws_size,
                              hipStream_t stream){
    const float* x      = (const float*)d_in[0];
    const float* A      = (const float*)d_in[1];
    const float* Bm     = (const float*)d_in[2];
    const float* C_q    = (const float*)d_in[3];
    const float* C_k    = (const float*)d_in[4];
    const float* C_v    = (const float*)d_in[5];
    const float* C_o    = (const float*)d_in[6];
    const float* C_fc   = (const float*)d_in[7];
    const float* C_proj = (const float*)d_in[8];
    const float* scale1 = (const float*)d_in[9];
    const float* scale2 = (const float*)d_in[10];
    float* out = (float*)d_out;

    char* ws = (char*)d_ws;
    size_t off = 0;
    auto alloc = [&](size_t bytes)->char*{ char* p = ws + off; off += (bytes + 255) & ~(size_t)255; return p; };
    unsigned short* qb   = (unsigned short*)alloc((size_t)Mn * Dn * 2);   // 8MB
    char*           Kimg = alloc((size_t)16 * 32 * 16384);                // 8MB
    char*           Vimg = alloc((size_t)16 * 32 * 16384);                // 8MB
    unsigned short* ybf  = (unsigned short*)alloc((size_t)Mn * Dn * 2);   // 8MB
    float*          pacc = (float*)alloc((size_t)256 * 16384 * 4);        // 16MB
    float2*         pml  = (float2*)alloc((size_t)256 * 128 * 8);         // 256KB
    float*          tp   = (float*)alloc(4 * TSTRIDE * 4);                // 4MB
    float*          ssp  = (float*)alloc(4 * (size_t)Mn * 4);             // 64KB
    unsigned short* At0  = (unsigned short*)alloc(65536 * 2);
    unsigned short* At1  = (unsigned short*)alloc(65536 * 2);
    unsigned short* At2  = (unsigned short*)alloc(65536 * 2);
    unsigned short* Btq  = (unsigned short*)alloc(65536 * 2);
    unsigned short* Btk  = (unsigned short*)alloc(65536 * 2);
    unsigned short* Btv  = (unsigned short*)alloc(65536 * 2);
    unsigned short* Bto  = (unsigned short*)alloc(65536 * 2);
    unsigned short* Btfc = (unsigned short*)alloc(65536 * 2);
    unsigned short* Btpr = (unsigned short*)alloc(65536 * 2);
    float2*         rt   = (float2*)alloc((size_t)Sn * 64 * 8);           // 1MB
    unsigned short* mb   = (unsigned short*)Kimg;  // overlay: Kimg dead after attention

    prep_g<<<2816, 256, 0, stream>>>(A, Bm, C_q, C_k, C_v, C_o, C_fc, C_proj,
                                     scale1, scale2, At0, At1, At2,
                                     Btq, Btk, Btv, Bto, Btfc, Btpr, rt);
    // t1 partials = x @ At1 (s1 folded), ss = rowwise sumsq(x)
    down_g<0, 1><<<dim3(Mn / 64, 4), 256, 0, stream>>>(x, At1, tp, ssp);
    // q (roped) -> qb; k (roped) -> Kimg; v^T -> Vimg ; rms fused in staging
    qkv_g<<<dim3(Mn / 64, 4), 256, 0, stream>>>(tp, ssp, Btq, Btk, Btv, rt, qb, Kimg, Vimg);
    // K-split flash attention + combine
    attn2_kernel<<<384, 256, 0, stream>>>(qb, Kimg, Vimg, ybf, pacc, pml);
    comb_g<<<128, 256, 0, stream>>>(pacc, pml, ybf);
    // t2 partials = y @ At0
    down_g<1, 0><<<dim3(Mn / 64, 4), 256, 0, stream>>>(ybf, At0, tp, nullptr);
    // x1 = x + t2 @ Bto
    up_g<0, 1, 0, 0><<<dim3(Mn / 32, 4), 256, 0, stream>>>(tp, nullptr, Bto, x, out);
    // t3 partials = x1 @ At2 (s2 folded), ss = sumsq(x1)
    down_g<0, 1><<<dim3(Mn / 64, 4), 256, 0, stream>>>(out, At2, tp, ssp);
    // mb = silu(rms-scaled t3 @ Btfc) (bf16)
    up_g<1, 0, 1, 1><<<dim3(Mn / 32, 4), 256, 0, stream>>>(tp, ssp, Btfc, nullptr, mb);
    // t4 partials = mb @ At0
    down_g<1, 0><<<dim3(Mn / 64, 4), 256, 0, stream>>>(mb, At0, tp, nullptr);
    // out = x1 + t4 @ Btpr
    up_g<0, 1, 0, 0><<<dim3(Mn / 32, 4), 256, 0, stream>>>(tp, nullptr, Btpr, out, out);
}